// Round 4
// baseline (2016.016 us; speedup 1.0000x reference)
//
#include <hip/hip_runtime.h>
#include <hip/hip_fp16.h>

// TemporalGCN: 2-layer GCN (gcn_norm, self-loops) + linear head.
// N=100000, E=1.6M, dims 128->64->64->16.
//
// R2: fp32-atomic push scatter = TCC atomic-rate bound (400MB WRITE/layer).
// R3: CSR+pull; bucket_kernel now dominates (134us, 106MB scattered 4B writes).
// R4: coarse buckets (128 nodes) + LDS-resident f32 accumulation.
//     - passB writes 1 packed u32/edge appended per bucket (dense lines).
//     - per-node degree recomputed per bucket from the bucketed stream.
//     - dinv[src] premultiplied into fp16 message table at GEMM epilogue,
//       so the agg inner loop is: shfl-broadcast, th gather, LDS atomicAdd.

constexpr int ID = 128;   // input dim
constexpr int HD = 64;    // hidden dim
constexpr int OD = 16;    // output dim
constexpr int RB = 128;   // nodes per coarse bucket
constexpr int MAXK = 1024;

// ---- pass A: coarse histogram of dst>>7 (K buckets) ----
__global__ __launch_bounds__(256) void passA_kernel(const int4* __restrict__ dst4,
                                                    int* __restrict__ cnt, int E4, int K) {
    __shared__ int h[MAXK];
    int tid = threadIdx.x;
    for (int i = tid; i < K; i += 256) h[i] = 0;
    __syncthreads();
    int id = blockIdx.x * 256 + tid, n = gridDim.x * 256;
    for (int i = id; i < E4; i += n) {
        int4 d = dst4[i];
        atomicAdd(&h[d.x >> 7], 1); atomicAdd(&h[d.y >> 7], 1);
        atomicAdd(&h[d.z >> 7], 1); atomicAdd(&h[d.w >> 7], 1);
    }
    __syncthreads();
    for (int i = tid; i < K; i += 256) if (h[i]) atomicAdd(&cnt[i], h[i]);
}

// ---- coarse scan: cnt[K] -> coff[K+1] (exclusive), cursor[K] ----
__global__ __launch_bounds__(1024) void cscan_kernel(const int* __restrict__ cnt,
                                                     int* __restrict__ coff,
                                                     int* __restrict__ cursor, int K, int E) {
    __shared__ int ts[MAXK];
    int tid = threadIdx.x;
    int v = (tid < K) ? cnt[tid] : 0;
    ts[tid] = v; __syncthreads();
    for (int d = 1; d < MAXK; d <<= 1) {
        int t = (tid >= d) ? ts[tid - d] : 0;
        __syncthreads();
        ts[tid] += t;
        __syncthreads();
    }
    if (tid < K) { int excl = ts[tid] - v; coff[tid] = excl; cursor[tid] = excl; }
    if (tid == 0) coff[K] = E;
}

// ---- pass B: append packed (local_dst<<20 | src) into bucket regions ----
__global__ __launch_bounds__(256) void passB_kernel(const int4* __restrict__ s4,
                                                    const int4* __restrict__ d4,
                                                    int* __restrict__ cursor,
                                                    unsigned* __restrict__ epk, int E4) {
    int id = blockIdx.x * 256 + threadIdx.x, n = gridDim.x * 256;
    for (int i = id; i < E4; i += n) {
        int4 s = s4[i]; int4 d = d4[i];
        int p;
        p = atomicAdd(&cursor[d.x >> 7], 1); epk[p] = ((unsigned)(d.x & 127) << 20) | (unsigned)s.x;
        p = atomicAdd(&cursor[d.y >> 7], 1); epk[p] = ((unsigned)(d.y & 127) << 20) | (unsigned)s.y;
        p = atomicAdd(&cursor[d.z >> 7], 1); epk[p] = ((unsigned)(d.z & 127) << 20) | (unsigned)s.z;
        p = atomicAdd(&cursor[d.w >> 7], 1); epk[p] = ((unsigned)(d.w & 127) << 20) | (unsigned)s.w;
    }
}

// ---- per-bucket degree recount -> dinv = rsqrt(deg+1) ----
__global__ __launch_bounds__(256) void deginv_kernel(const int* __restrict__ coff,
                                                     const unsigned* __restrict__ epk,
                                                     float* __restrict__ dinv, int N) {
    __shared__ int dg[RB];
    int b = blockIdx.x, tid = threadIdx.x, base = b * RB;
    if (tid < RB) dg[tid] = 0;
    __syncthreads();
    int e0 = coff[b], e1 = coff[b + 1];
    for (int e = e0 + tid; e < e1; e += 256) atomicAdd(&dg[epk[e] >> 20], 1);
    __syncthreads();
    if (tid < RB && base + tid < N) dinv[base + tid] = rsqrtf((float)dg[tid] + 1.0f);
}

// ---- GEMM1: th = fp16( (x @ W1) * dinv[row] )  [N,128]x[128,64] ----
__global__ __launch_bounds__(256) void gemm1_kernel(
    const float* __restrict__ x, const float* __restrict__ W,
    const float* __restrict__ dinv, __half* __restrict__ th, int N) {
    __shared__ float Ws[ID * HD];   // 32 KB
    __shared__ float xs[8][ID];     // 4 KB
    int tid = threadIdx.x;
    for (int i = tid; i < (ID * HD) / 4; i += 256)
        ((float4*)Ws)[i] = ((const float4*)W)[i];
    int base = blockIdx.x * 8;
    {
        int elem = tid * 4;                 // 1024 floats = 256 float4
        int r = elem >> 7, c = elem & (ID - 1);
        int row = base + r;
        float4 z4 = {0.f, 0.f, 0.f, 0.f};
        *(float4*)&xs[r][c] = (row < N) ? *(const float4*)&x[(size_t)row * ID + c] : z4;
    }
    __syncthreads();
    int col = tid & 63;
    int rg  = tid >> 6;  // 4 waves, 2 rows each
    float acc0 = 0.f, acc1 = 0.f;
    #pragma unroll 8
    for (int k = 0; k < ID; ++k) {
        float w = Ws[k * HD + col];
        acc0 += xs[rg * 2][k] * w;
        acc1 += xs[rg * 2 + 1][k] * w;
    }
    int r0 = base + rg * 2, r1 = r0 + 1;
    if (r0 < N) th[(size_t)r0 * HD + col] = __float2half(acc0 * dinv[r0]);
    if (r1 < N) th[(size_t)r1 * HD + col] = __float2half(acc1 * dinv[r1]);
}

// ---- aggregation: one block per bucket, LDS f32 accumulator ----
// a[d] = dinv[d] * ( sum_{s in N(d)} th'[s] + th'[d] ),  th' = dinv*h (fp16)
__global__ __launch_bounds__(512) void agg_kernel(
    const int* __restrict__ coff, const unsigned* __restrict__ epk,
    const float* __restrict__ dinv, const __half* __restrict__ th,
    float* __restrict__ a, int N) {
    __shared__ float acc[RB * HD];  // 32 KB
    int tid = threadIdx.x, b = blockIdx.x, base = b * RB;
    float4 z4 = {0.f, 0.f, 0.f, 0.f};
    for (int i = tid * 4; i < RB * HD; i += 512 * 4) *(float4*)&acc[i] = z4;
    __syncthreads();
    int e0 = coff[b], e1 = coff[b + 1];
    int lane = tid & 63, wv = tid >> 6;   // 8 waves
    for (int cb = e0 + wv * 64; cb < e1; cb += 8 * 64) {
        int idx = cb + lane;
        unsigned pk = (idx < e1) ? epk[idx] : 0u;
        int cnt = min(64, e1 - cb);
        #pragma unroll 4
        for (int i = 0; i < cnt; ++i) {
            unsigned pki = __shfl(pk, i);       // uniform broadcast
            int si = pki & 0xFFFFF;
            int ld = pki >> 20;
            float msg = __half2float(th[(size_t)si * HD + lane]);
            atomicAdd(&acc[ld * HD + lane], msg);
        }
    }
    __syncthreads();
    for (int r = wv; r < RB; r += 8) {
        int d = base + r;
        if (d < N) {
            float dd = dinv[d];
            a[(size_t)d * HD + lane] =
                dd * (acc[r * HD + lane] + __half2float(th[(size_t)d * HD + lane]));
        }
    }
}

// ---- GEMM2: th = fp16( (relu(a1+b1) @ W2) * dinv[row] )  [N,64]x[64,64] ----
__global__ __launch_bounds__(256) void gemm2_kernel(
    const float* __restrict__ ain, const float* __restrict__ W,
    const float* __restrict__ bias, const float* __restrict__ dinv,
    __half* __restrict__ th, int N) {
    __shared__ float Ws[HD * HD];   // 16 KB
    __shared__ float hs[8][HD];     // 2 KB
    int tid = threadIdx.x;
    for (int i = tid; i < (HD * HD) / 4; i += 256)
        ((float4*)Ws)[i] = ((const float4*)W)[i];
    int base = blockIdx.x * 8;
    for (int i = tid; i < 8 * HD; i += 256) {
        int r = i >> 6, c = i & 63;
        int row = base + r;
        float v = (row < N) ? ain[(size_t)row * HD + c] + bias[c] : 0.0f;
        hs[r][c] = fmaxf(v, 0.0f);
    }
    __syncthreads();
    int col = tid & 63;
    int rg  = tid >> 6;
    float acc0 = 0.f, acc1 = 0.f;
    #pragma unroll 8
    for (int k = 0; k < HD; ++k) {
        float w = Ws[k * HD + col];
        acc0 += hs[rg * 2][k] * w;
        acc1 += hs[rg * 2 + 1][k] * w;
    }
    int r0 = base + rg * 2, r1 = r0 + 1;
    if (r0 < N) th[(size_t)r0 * HD + col] = __float2half(acc0 * dinv[r0]);
    if (r1 < N) th[(size_t)r1 * HD + col] = __float2half(acc1 * dinv[r1]);
}

// ---- head: out = (a2 + b2) @ Wc + bc   [N,64]x[64,16] ----
__global__ __launch_bounds__(256) void final_kernel(
    const float* __restrict__ ain, const float* __restrict__ b2,
    const float* __restrict__ Wc, const float* __restrict__ bc,
    float* __restrict__ out, int N) {
    __shared__ float Ws[HD * OD];     // 4 KB
    __shared__ float hs[16][HD + 1];  // padded
    int tid = threadIdx.x;
    for (int i = tid; i < HD * OD; i += 256) Ws[i] = Wc[i];
    int base = blockIdx.x * 16;
    for (int i = tid; i < 16 * HD; i += 256) {
        int r = i >> 6, c = i & 63;
        int row = base + r;
        hs[r][c] = (row < N) ? ain[(size_t)row * HD + c] + b2[c] : 0.0f;
    }
    __syncthreads();
    int col = tid & 15, r = tid >> 4;
    int row = base + r;
    if (row < N) {
        float acc = bc[col];
        #pragma unroll
        for (int k = 0; k < HD; ++k)
            acc += hs[r][k] * Ws[k * OD + col];
        out[(size_t)row * OD + col] = acc;
    }
}

extern "C" void kernel_launch(void* const* d_in, const int* in_sizes, int n_in,
                              void* d_out, int out_size, void* d_ws, size_t ws_size,
                              hipStream_t stream) {
    const float* x  = (const float*)d_in[0];
    const int*   ei = (const int*)d_in[1];   // [2,E] flat int32
    const float* W1 = (const float*)d_in[2];
    const float* b1 = (const float*)d_in[3];
    const float* W2 = (const float*)d_in[4];
    const float* b2 = (const float*)d_in[5];
    const float* Wc = (const float*)d_in[6];
    const float* bc = (const float*)d_in[7];
    float* out = (float*)d_out;

    int N = in_sizes[0] / ID;   // 100000
    int E = in_sizes[1] / 2;    // 1600000 (multiple of 4)
    const int* src = ei;
    const int* dst = ei + E;
    int K = (N + RB - 1) / RB;  // 782 coarse buckets (requires K <= MAXK)

    char* p = (char*)d_ws;
    int*      cnt    = (int*)p;      p += MAXK * 4;
    int*      coff   = (int*)p;      p += (MAXK + 4) * 4;
    int*      cursor = (int*)p;      p += MAXK * 4;
    float*    dinv   = (float*)p;    p += (size_t)((N + 63) & ~63) * 4;
    unsigned* epk    = (unsigned*)p; p += (size_t)E * 4;       // bucketed edges
    __half*   th     = (__half*)p;   p += (size_t)N * HD * 2;  // premult msgs
    float*    a1     = (float*)p;    p += (size_t)N * HD * 4;  // agg out (reused)

    hipMemsetAsync(cnt, 0, (size_t)K * sizeof(int), stream);

    // bucket build (shared by both layers)
    passA_kernel<<<512, 256, 0, stream>>>((const int4*)dst, cnt, E / 4, K);
    cscan_kernel<<<1, 1024, 0, stream>>>(cnt, coff, cursor, K, E);
    passB_kernel<<<512, 256, 0, stream>>>((const int4*)src, (const int4*)dst,
                                          cursor, epk, E / 4);
    deginv_kernel<<<K, 256, 0, stream>>>(coff, epk, dinv, N);

    // layer 1
    gemm1_kernel<<<(N + 7) / 8, 256, 0, stream>>>(x, W1, dinv, th, N);
    agg_kernel<<<K, 512, 0, stream>>>(coff, epk, dinv, th, a1, N);

    // layer 2
    gemm2_kernel<<<(N + 7) / 8, 256, 0, stream>>>(a1, W2, b1, dinv, th, N);
    agg_kernel<<<K, 512, 0, stream>>>(coff, epk, dinv, th, a1, N);

    // head
    final_kernel<<<(N + 15) / 16, 256, 0, stream>>>(a1, b2, Wc, bc, out, N);
}

// Round 6
// 758.054 us; speedup vs baseline: 2.6595x; 2.6595x over previous
//
#include <hip/hip_runtime.h>
#include <hip/hip_fp16.h>

// TemporalGCN: 2-layer GCN (gcn_norm, self-loops) + linear head.
// N=100000, E=1.6M, dims 128->64->64->16.
//
// R2: fp32-atomic push scatter = TCC atomic-rate bound (400MB WRITE/layer).
// R3: CSR+pull = 555us; bucket_kernel dominates (134us scattered 4B writes).
// R4: LDS-accumulate agg REGRESSED 7x (711us/layer): per-edge shfl->gather->
//     LDS-atomic chain is wave-serial, ~4 loads in flight, latency-exposed.
// R5: R3 structure + dense CSR build (coarse bucket append + per-bucket LDS
//     sort, all global writes dense/L2-resident) + pull with dinv premult
//     into fp16 messages (1 gather/edge) and x8 unroll for ILP.

constexpr int ID = 128;   // input dim
constexpr int HD = 64;    // hidden dim
constexpr int OD = 16;    // output dim
constexpr int RB = 128;   // nodes per coarse bucket
constexpr int MAXK = 1024;

// ---- pass A: coarse histogram of dst>>7 (K buckets) ----
__global__ __launch_bounds__(256) void passA_kernel(const int4* __restrict__ dst4,
                                                    int* __restrict__ cnt, int E4, int K) {
    __shared__ int h[MAXK];
    int tid = threadIdx.x;
    for (int i = tid; i < K; i += 256) h[i] = 0;
    __syncthreads();
    int id = blockIdx.x * 256 + tid, n = gridDim.x * 256;
    for (int i = id; i < E4; i += n) {
        int4 d = dst4[i];
        atomicAdd(&h[d.x >> 7], 1); atomicAdd(&h[d.y >> 7], 1);
        atomicAdd(&h[d.z >> 7], 1); atomicAdd(&h[d.w >> 7], 1);
    }
    __syncthreads();
    for (int i = tid; i < K; i += 256) if (h[i]) atomicAdd(&cnt[i], h[i]);
}

// ---- coarse scan: cnt[K] -> coff[K+1] (exclusive), cursor[K] ----
__global__ __launch_bounds__(1024) void cscan_kernel(const int* __restrict__ cnt,
                                                     int* __restrict__ coff,
                                                     int* __restrict__ cursor, int K, int E) {
    __shared__ int ts[MAXK];
    int tid = threadIdx.x;
    int v = (tid < K) ? cnt[tid] : 0;
    ts[tid] = v; __syncthreads();
    for (int d = 1; d < MAXK; d <<= 1) {
        int t = (tid >= d) ? ts[tid - d] : 0;
        __syncthreads();
        ts[tid] += t;
        __syncthreads();
    }
    if (tid < K) { int excl = ts[tid] - v; coff[tid] = excl; cursor[tid] = excl; }
    if (tid == 0) coff[K] = E;
}

// ---- pass B: append packed (local_dst<<20 | src) into bucket regions ----
__global__ __launch_bounds__(256) void passB_kernel(const int4* __restrict__ s4,
                                                    const int4* __restrict__ d4,
                                                    int* __restrict__ cursor,
                                                    unsigned* __restrict__ epk, int E4) {
    int id = blockIdx.x * 256 + threadIdx.x, n = gridDim.x * 256;
    for (int i = id; i < E4; i += n) {
        int4 s = s4[i]; int4 d = d4[i];
        int p;
        p = atomicAdd(&cursor[d.x >> 7], 1); epk[p] = ((unsigned)(d.x & 127) << 20) | (unsigned)s.x;
        p = atomicAdd(&cursor[d.y >> 7], 1); epk[p] = ((unsigned)(d.y & 127) << 20) | (unsigned)s.y;
        p = atomicAdd(&cursor[d.z >> 7], 1); epk[p] = ((unsigned)(d.z & 127) << 20) | (unsigned)s.z;
        p = atomicAdd(&cursor[d.w >> 7], 1); epk[p] = ((unsigned)(d.w & 127) << 20) | (unsigned)s.w;
    }
}

// ---- per-bucket sort -> exact CSR (off, sse) + dinv. One block per bucket;
// all reads/writes confined to the bucket's contiguous ~8KB region.
__global__ __launch_bounds__(256) void sortB_kernel(
    const int* __restrict__ coff, const unsigned* __restrict__ epk,
    int* __restrict__ sse, int* __restrict__ off,
    float* __restrict__ dinv, int N) {
    __shared__ int hist[RB];
    __shared__ int lofs[RB];
    int b = blockIdx.x, tid = threadIdx.x, base = b * RB;
    if (tid < RB) hist[tid] = 0;
    __syncthreads();
    int e0 = coff[b], e1 = coff[b + 1];
    // pass 1: local in-degree histogram
    for (int e = e0 + tid; e < e1; e += 256)
        atomicAdd(&hist[epk[e] >> 20], 1);
    __syncthreads();
    // exclusive scan of hist[128]
    if (tid < RB) lofs[tid] = hist[tid];
    __syncthreads();
    for (int d = 1; d < RB; d <<= 1) {
        int t = (tid < RB && tid >= d) ? lofs[tid - d] : 0;
        __syncthreads();
        if (tid < RB) lofs[tid] += t;
        __syncthreads();
    }
    if (tid < RB) {
        int excl = lofs[tid] - hist[tid];
        int node = base + tid;
        if (node <= N) off[node] = e0 + excl;   // off[N] covered by last bucket
        if (node < N)  dinv[node] = rsqrtf((float)hist[tid] + 1.0f);
        lofs[tid] = e0 + excl;                  // global write cursor
    }
    __syncthreads();
    // pass 2: scatter src into per-node segments (bucket region is L2-warm)
    for (int e = e0 + tid; e < e1; e += 256) {
        unsigned pk = epk[e];
        int pos = atomicAdd(&lofs[pk >> 20], 1);
        sse[pos] = (int)(pk & 0xFFFFF);
    }
}

// ---- GEMM1: th = fp16( (x @ W1) * dinv[row] )  [N,128]x[128,64] ----
__global__ __launch_bounds__(256) void gemm1_kernel(
    const float* __restrict__ x, const float* __restrict__ W,
    const float* __restrict__ dinv, __half* __restrict__ th, int N) {
    __shared__ float Ws[ID * HD];   // 32 KB
    __shared__ float xs[8][ID];     // 4 KB
    int tid = threadIdx.x;
    for (int i = tid; i < (ID * HD) / 4; i += 256)
        ((float4*)Ws)[i] = ((const float4*)W)[i];
    int base = blockIdx.x * 8;
    {
        int elem = tid * 4;                 // 1024 floats = 256 float4
        int r = elem >> 7, c = elem & (ID - 1);
        int row = base + r;
        float4 z4 = {0.f, 0.f, 0.f, 0.f};
        *(float4*)&xs[r][c] = (row < N) ? *(const float4*)&x[(size_t)row * ID + c] : z4;
    }
    __syncthreads();
    int col = tid & 63;
    int rg  = tid >> 6;  // 4 waves, 2 rows each
    float acc0 = 0.f, acc1 = 0.f;
    #pragma unroll 8
    for (int k = 0; k < ID; ++k) {
        float w = Ws[k * HD + col];
        acc0 += xs[rg * 2][k] * w;
        acc1 += xs[rg * 2 + 1][k] * w;
    }
    int r0 = base + rg * 2, r1 = r0 + 1;
    if (r0 < N) th[(size_t)r0 * HD + col] = __float2half(acc0 * dinv[r0]);
    if (r1 < N) th[(size_t)r1 * HD + col] = __float2half(acc1 * dinv[r1]);
}

// ---- pull: one wave per node, lane = feature. th is dinv-premultiplied:
// a[d] = dinv[d] * ( sum_{s in N(d)} th'[s] + th'[d] )
__global__ __launch_bounds__(256) void pull_kernel(
    const int* __restrict__ off, const int* __restrict__ sse,
    const float* __restrict__ dinv, const __half* __restrict__ th,
    float* __restrict__ a, int N) {
    int lane = threadIdx.x & 63;
    int w = (blockIdx.x * blockDim.x + threadIdx.x) >> 6;
    if (w >= N) return;
    int o0 = off[w], o1 = off[w + 1];
    float acc = 0.f;
    int j = o0;
    for (; j + 7 < o1; j += 8) {
        int s0 = sse[j],   s1 = sse[j+1], s2 = sse[j+2], s3 = sse[j+3];
        int s4 = sse[j+4], s5 = sse[j+5], s6 = sse[j+6], s7 = sse[j+7];
        float t0 = __half2float(th[(size_t)s0 * HD + lane]);
        float t1 = __half2float(th[(size_t)s1 * HD + lane]);
        float t2 = __half2float(th[(size_t)s2 * HD + lane]);
        float t3 = __half2float(th[(size_t)s3 * HD + lane]);
        float t4 = __half2float(th[(size_t)s4 * HD + lane]);
        float t5 = __half2float(th[(size_t)s5 * HD + lane]);
        float t6 = __half2float(th[(size_t)s6 * HD + lane]);
        float t7 = __half2float(th[(size_t)s7 * HD + lane]);
        acc += ((t0 + t1) + (t2 + t3)) + ((t4 + t5) + (t6 + t7));
    }
    for (; j < o1; ++j)
        acc += __half2float(th[(size_t)sse[j] * HD + lane]);
    a[(size_t)w * HD + lane] =
        dinv[w] * (acc + __half2float(th[(size_t)w * HD + lane]));
}

// ---- GEMM2: th = fp16( (relu(a1+b1) @ W2) * dinv[row] )  [N,64]x[64,64] ----
__global__ __launch_bounds__(256) void gemm2_kernel(
    const float* __restrict__ ain, const float* __restrict__ W,
    const float* __restrict__ bias, const float* __restrict__ dinv,
    __half* __restrict__ th, int N) {
    __shared__ float Ws[HD * HD];   // 16 KB
    __shared__ float hs[8][HD];     // 2 KB
    int tid = threadIdx.x;
    for (int i = tid; i < (HD * HD) / 4; i += 256)
        ((float4*)Ws)[i] = ((const float4*)W)[i];
    int base = blockIdx.x * 8;
    for (int i = tid; i < 8 * HD; i += 256) {
        int r = i >> 6, c = i & 63;
        int row = base + r;
        float v = (row < N) ? ain[(size_t)row * HD + c] + bias[c] : 0.0f;
        hs[r][c] = fmaxf(v, 0.0f);
    }
    __syncthreads();
    int col = tid & 63;
    int rg  = tid >> 6;
    float acc0 = 0.f, acc1 = 0.f;
    #pragma unroll 8
    for (int k = 0; k < HD; ++k) {
        float w = Ws[k * HD + col];
        acc0 += hs[rg * 2][k] * w;
        acc1 += hs[rg * 2 + 1][k] * w;
    }
    int r0 = base + rg * 2, r1 = r0 + 1;
    if (r0 < N) th[(size_t)r0 * HD + col] = __float2half(acc0 * dinv[r0]);
    if (r1 < N) th[(size_t)r1 * HD + col] = __float2half(acc1 * dinv[r1]);
}

// ---- head: out = (a2 + b2) @ Wc + bc   [N,64]x[64,16] ----
__global__ __launch_bounds__(256) void final_kernel(
    const float* __restrict__ ain, const float* __restrict__ b2,
    const float* __restrict__ Wc, const float* __restrict__ bc,
    float* __restrict__ out, int N) {
    __shared__ float Ws[HD * OD];     // 4 KB
    __shared__ float hs[16][HD + 1];  // padded
    int tid = threadIdx.x;
    for (int i = tid; i < HD * OD; i += 256) Ws[i] = Wc[i];
    int base = blockIdx.x * 16;
    for (int i = tid; i < 16 * HD; i += 256) {
        int r = i >> 6, c = i & 63;
        int row = base + r;
        hs[r][c] = (row < N) ? ain[(size_t)row * HD + c] + b2[c] : 0.0f;
    }
    __syncthreads();
    int col = tid & 15, r = tid >> 4;
    int row = base + r;
    if (row < N) {
        float acc = bc[col];
        #pragma unroll
        for (int k = 0; k < HD; ++k)
            acc += hs[r][k] * Ws[k * OD + col];
        out[(size_t)row * OD + col] = acc;
    }
}

extern "C" void kernel_launch(void* const* d_in, const int* in_sizes, int n_in,
                              void* d_out, int out_size, void* d_ws, size_t ws_size,
                              hipStream_t stream) {
    const float* x  = (const float*)d_in[0];
    const int*   ei = (const int*)d_in[1];   // [2,E] flat int32
    const float* W1 = (const float*)d_in[2];
    const float* b1 = (const float*)d_in[3];
    const float* W2 = (const float*)d_in[4];
    const float* b2 = (const float*)d_in[5];
    const float* Wc = (const float*)d_in[6];
    const float* bc = (const float*)d_in[7];
    float* out = (float*)d_out;

    int N = in_sizes[0] / ID;   // 100000
    int E = in_sizes[1] / 2;    // 1600000 (multiple of 4)
    const int* src = ei;
    const int* dst = ei + E;
    int K = (N + RB - 1) / RB;  // 782 coarse buckets (K <= MAXK)
    int Npad = (N + 63) & ~63;

    char* p = (char*)d_ws;
    int*      cnt    = (int*)p;      p += MAXK * 4;
    int*      coff   = (int*)p;      p += (MAXK + 4) * 4;
    int*      cursor = (int*)p;      p += MAXK * 4;
    float*    dinv   = (float*)p;    p += (size_t)Npad * 4;
    int*      off    = (int*)p;      p += (size_t)(Npad + 128) * 4;
    unsigned* epk    = (unsigned*)p; p += (size_t)E * 4;       // bucketed packed edges
    int*      sse    = (int*)p;      p += (size_t)E * 4;       // CSR src, dst-sorted
    __half*   th     = (__half*)p;   p += (size_t)N * HD * 2;  // dinv-premult msgs
    float*    a1     = (float*)p;    p += (size_t)N * HD * 4;  // agg out (reused)

    hipMemsetAsync(cnt, 0, (size_t)K * sizeof(int), stream);

    // dense CSR build (shared by both layers)
    passA_kernel<<<512, 256, 0, stream>>>((const int4*)dst, cnt, E / 4, K);
    cscan_kernel<<<1, 1024, 0, stream>>>(cnt, coff, cursor, K, E);
    passB_kernel<<<512, 256, 0, stream>>>((const int4*)src, (const int4*)dst,
                                          cursor, epk, E / 4);
    sortB_kernel<<<K, 256, 0, stream>>>(coff, epk, sse, off, dinv, N);

    // layer 1
    gemm1_kernel<<<(N + 7) / 8, 256, 0, stream>>>(x, W1, dinv, th, N);
    pull_kernel<<<(N * 64 + 255) / 256, 256, 0, stream>>>(off, sse, dinv, th, a1, N);

    // layer 2
    gemm2_kernel<<<(N + 7) / 8, 256, 0, stream>>>(a1, W2, b1, dinv, th, N);
    pull_kernel<<<(N * 64 + 255) / 256, 256, 0, stream>>>(off, sse, dinv, th, a1, N);

    // head
    final_kernel<<<(N + 15) / 16, 256, 0, stream>>>(a1, b2, Wc, bc, out, N);
}

// Round 7
// 399.841 us; speedup vs baseline: 5.0420x; 1.8959x over previous
//
#include <hip/hip_runtime.h>
#include <hip/hip_fp16.h>

// TemporalGCN: 2-layer GCN (gcn_norm, self-loops) + linear head.
// N=100000, E=1.6M, dims 128->64->64->16.
//
// R2: fp32-atomic push scatter = TCC atomic-rate bound (400MB WRITE/layer).
// R3: CSR+pull = 555us; bucket_kernel dominates (134us scattered 4B writes,
//     ~790GB/s random-line write bound; 100K cursors -> low atomic contention).
// R4: LDS-accumulate agg regressed 7x: per-edge shfl->gather->LDS-atomic is
//     wave-serial, latency-exposed.
// R6: passB with 782 global cursors = atomic-CONTENTION bound (377us,
//     VALUBusy 0.09%, HBM 2.6%): 1.6M atomicAdd-with-return over 782 addrs.
// R7: block-staged passB: per-chunk LDS histogram + ONE global atomicAdd per
//     (chunk,bucket) reservation + LDS reorder + grouped coalesced writeout.
//     RB=512 (K=196 buckets), payload = (local_dst<<17|src), src<2^17.

constexpr int ID = 128;   // input dim
constexpr int HD = 64;    // hidden dim
constexpr int OD = 16;    // output dim
constexpr int RB = 512;   // nodes per coarse bucket
constexpr int KMAX = 256; // max buckets (K = ceil(N/RB) = 196)
constexpr int CHUNK = 4096;

// ---- pass A: coarse histogram of dst>>9 ----
__global__ __launch_bounds__(256) void passA_kernel(const int4* __restrict__ dst4,
                                                    int* __restrict__ cnt, int E4, int K) {
    __shared__ int h[KMAX];
    int tid = threadIdx.x;
    for (int i = tid; i < K; i += 256) h[i] = 0;
    __syncthreads();
    int id = blockIdx.x * 256 + tid, n = gridDim.x * 256;
    for (int i = id; i < E4; i += n) {
        int4 d = dst4[i];
        atomicAdd(&h[d.x >> 9], 1); atomicAdd(&h[d.y >> 9], 1);
        atomicAdd(&h[d.z >> 9], 1); atomicAdd(&h[d.w >> 9], 1);
    }
    __syncthreads();
    for (int i = tid; i < K; i += 256) if (h[i]) atomicAdd(&cnt[i], h[i]);
}

// ---- coarse scan: cnt[K] -> coff[K+1] (exclusive), cursor[K] ----
__global__ __launch_bounds__(256) void cscan_kernel(const int* __restrict__ cnt,
                                                    int* __restrict__ coff,
                                                    int* __restrict__ cursor, int K, int E) {
    __shared__ int ts[KMAX];
    int tid = threadIdx.x;
    int v = (tid < K) ? cnt[tid] : 0;
    ts[tid] = v; __syncthreads();
    for (int d = 1; d < KMAX; d <<= 1) {
        int t = (tid >= d) ? ts[tid - d] : 0;
        __syncthreads();
        ts[tid] += t;
        __syncthreads();
    }
    if (tid < K) { int excl = ts[tid] - v; coff[tid] = excl; cursor[tid] = excl; }
    if (tid == 0) coff[K] = E;
}

// ---- pass B (block-staged): chunk -> LDS histogram -> one global atomicAdd
// per (chunk,bucket) -> LDS reorder -> bucket-grouped coalesced writeout.
__global__ __launch_bounds__(256) void passB_kernel(const int* __restrict__ src,
                                                    const int* __restrict__ dst,
                                                    int* __restrict__ cursor,
                                                    unsigned* __restrict__ epk, int E) {
    __shared__ unsigned      buf[CHUNK];      // 16 KB  reordered payloads
    __shared__ unsigned char bkt[CHUNK];      //  4 KB  bucket of each slot
    __shared__ int hist[KMAX], lofs[KMAX], gpos[KMAX], ts[KMAX];
    int tid = threadIdx.x;
    int base = blockIdx.x * CHUNK;
    int cnt = min(CHUNK, E - base);

    for (int i = tid; i < KMAX; i += 256) hist[i] = 0;
    __syncthreads();

    // phase 1: load, count, remember rank
    unsigned mypay[CHUNK / 256];
    short    myb[CHUNK / 256];
    short    myrank[CHUNK / 256];
    #pragma unroll
    for (int j = 0; j < CHUNK / 256; ++j) {
        int o = j * 256 + tid;
        myb[j] = -1;
        if (o < cnt) {
            int d = dst[base + o], s = src[base + o];
            int b = d >> 9;
            myb[j] = (short)b;
            myrank[j] = (short)atomicAdd(&hist[b], 1);
            mypay[j] = ((unsigned)(d & (RB - 1)) << 17) | (unsigned)s;
        }
    }
    __syncthreads();

    // exclusive scan of hist -> lofs; global range reservation -> gpos
    int v = hist[tid];
    ts[tid] = v; __syncthreads();
    for (int d = 1; d < KMAX; d <<= 1) {
        int t = (tid >= d) ? ts[tid - d] : 0;
        __syncthreads();
        ts[tid] += t;
        __syncthreads();
    }
    lofs[tid] = ts[tid] - v;
    if (v > 0) gpos[tid] = atomicAdd(&cursor[tid], v);
    __syncthreads();

    // phase 2: reorder into LDS, grouped by bucket
    #pragma unroll
    for (int j = 0; j < CHUNK / 256; ++j) {
        if (myb[j] >= 0) {
            int pos = lofs[myb[j]] + myrank[j];
            buf[pos] = mypay[j];
            bkt[pos] = (unsigned char)myb[j];
        }
    }
    __syncthreads();

    // phase 3: linear copy-out; consecutive i within a group -> consecutive
    // global addresses (runs of ~CHUNK/K edges, mostly full lines)
    for (int i = tid; i < cnt; i += 256) {
        int b = bkt[i];
        epk[gpos[b] + (i - lofs[b])] = buf[i];
    }
}

// ---- per-bucket sort -> exact CSR (off, sse) + dinv. One block per bucket;
// reads/writes confined to the bucket's contiguous ~32KB L2-warm region.
__global__ __launch_bounds__(512) void sortB_kernel(
    const int* __restrict__ coff, const unsigned* __restrict__ epk,
    int* __restrict__ sse, int* __restrict__ off,
    float* __restrict__ dinv, int N) {
    __shared__ int hist[RB];
    __shared__ int lofs[RB];
    __shared__ int ts[RB];
    int b = blockIdx.x, tid = threadIdx.x, base = b * RB;
    hist[tid] = 0;
    __syncthreads();
    int e0 = coff[b], e1 = coff[b + 1];
    // pass 1: local in-degree histogram
    for (int e = e0 + tid; e < e1; e += 512)
        atomicAdd(&hist[epk[e] >> 17], 1);
    __syncthreads();
    // exclusive scan of hist[512]
    int v = hist[tid];
    ts[tid] = v; __syncthreads();
    for (int d = 1; d < RB; d <<= 1) {
        int t = (tid >= d) ? ts[tid - d] : 0;
        __syncthreads();
        ts[tid] += t;
        __syncthreads();
    }
    {
        int excl = ts[tid] - v;
        int node = base + tid;
        if (node <= N) off[node] = e0 + excl;   // off[N] covered by last bucket
        if (node < N)  dinv[node] = rsqrtf((float)v + 1.0f);
        lofs[tid] = e0 + excl;                  // global write cursor
    }
    __syncthreads();
    // pass 2: scatter src into per-node segments (L2-warm window)
    for (int e = e0 + tid; e < e1; e += 512) {
        unsigned pk = epk[e];
        int pos = atomicAdd(&lofs[pk >> 17], 1);
        sse[pos] = (int)(pk & 0x1FFFF);
    }
}

// ---- GEMM1: th = fp16( (x @ W1) * dinv[row] )  [N,128]x[128,64] ----
__global__ __launch_bounds__(256) void gemm1_kernel(
    const float* __restrict__ x, const float* __restrict__ W,
    const float* __restrict__ dinv, __half* __restrict__ th, int N) {
    __shared__ float Ws[ID * HD];   // 32 KB
    __shared__ float xs[8][ID];     // 4 KB
    int tid = threadIdx.x;
    for (int i = tid; i < (ID * HD) / 4; i += 256)
        ((float4*)Ws)[i] = ((const float4*)W)[i];
    int base = blockIdx.x * 8;
    {
        int elem = tid * 4;                 // 1024 floats = 256 float4
        int r = elem >> 7, c = elem & (ID - 1);
        int row = base + r;
        float4 z4 = {0.f, 0.f, 0.f, 0.f};
        *(float4*)&xs[r][c] = (row < N) ? *(const float4*)&x[(size_t)row * ID + c] : z4;
    }
    __syncthreads();
    int col = tid & 63;
    int rg  = tid >> 6;  // 4 waves, 2 rows each
    float acc0 = 0.f, acc1 = 0.f;
    #pragma unroll 8
    for (int k = 0; k < ID; ++k) {
        float w = Ws[k * HD + col];
        acc0 += xs[rg * 2][k] * w;
        acc1 += xs[rg * 2 + 1][k] * w;
    }
    int r0 = base + rg * 2, r1 = r0 + 1;
    if (r0 < N) th[(size_t)r0 * HD + col] = __float2half(acc0 * dinv[r0]);
    if (r1 < N) th[(size_t)r1 * HD + col] = __float2half(acc1 * dinv[r1]);
}

// ---- pull: one wave per node, lane = feature. th is dinv-premultiplied:
// a[d] = dinv[d] * ( sum_{s in N(d)} th'[s] + th'[d] )
__global__ __launch_bounds__(256) void pull_kernel(
    const int* __restrict__ off, const int* __restrict__ sse,
    const float* __restrict__ dinv, const __half* __restrict__ th,
    float* __restrict__ a, int N) {
    int lane = threadIdx.x & 63;
    int w = (blockIdx.x * blockDim.x + threadIdx.x) >> 6;
    if (w >= N) return;
    int o0 = off[w], o1 = off[w + 1];
    float acc = 0.f;
    int j = o0;
    for (; j + 7 < o1; j += 8) {
        int s0 = sse[j],   s1 = sse[j+1], s2 = sse[j+2], s3 = sse[j+3];
        int s4 = sse[j+4], s5 = sse[j+5], s6 = sse[j+6], s7 = sse[j+7];
        float t0 = __half2float(th[(size_t)s0 * HD + lane]);
        float t1 = __half2float(th[(size_t)s1 * HD + lane]);
        float t2 = __half2float(th[(size_t)s2 * HD + lane]);
        float t3 = __half2float(th[(size_t)s3 * HD + lane]);
        float t4 = __half2float(th[(size_t)s4 * HD + lane]);
        float t5 = __half2float(th[(size_t)s5 * HD + lane]);
        float t6 = __half2float(th[(size_t)s6 * HD + lane]);
        float t7 = __half2float(th[(size_t)s7 * HD + lane]);
        acc += ((t0 + t1) + (t2 + t3)) + ((t4 + t5) + (t6 + t7));
    }
    for (; j < o1; ++j)
        acc += __half2float(th[(size_t)sse[j] * HD + lane]);
    a[(size_t)w * HD + lane] =
        dinv[w] * (acc + __half2float(th[(size_t)w * HD + lane]));
}

// ---- GEMM2: th = fp16( (relu(a1+b1) @ W2) * dinv[row] )  [N,64]x[64,64] ----
__global__ __launch_bounds__(256) void gemm2_kernel(
    const float* __restrict__ ain, const float* __restrict__ W,
    const float* __restrict__ bias, const float* __restrict__ dinv,
    __half* __restrict__ th, int N) {
    __shared__ float Ws[HD * HD];   // 16 KB
    __shared__ float hs[8][HD];     // 2 KB
    int tid = threadIdx.x;
    for (int i = tid; i < (HD * HD) / 4; i += 256)
        ((float4*)Ws)[i] = ((const float4*)W)[i];
    int base = blockIdx.x * 8;
    for (int i = tid; i < 8 * HD; i += 256) {
        int r = i >> 6, c = i & 63;
        int row = base + r;
        float v = (row < N) ? ain[(size_t)row * HD + c] + bias[c] : 0.0f;
        hs[r][c] = fmaxf(v, 0.0f);
    }
    __syncthreads();
    int col = tid & 63;
    int rg  = tid >> 6;
    float acc0 = 0.f, acc1 = 0.f;
    #pragma unroll 8
    for (int k = 0; k < HD; ++k) {
        float w = Ws[k * HD + col];
        acc0 += hs[rg * 2][k] * w;
        acc1 += hs[rg * 2 + 1][k] * w;
    }
    int r0 = base + rg * 2, r1 = r0 + 1;
    if (r0 < N) th[(size_t)r0 * HD + col] = __float2half(acc0 * dinv[r0]);
    if (r1 < N) th[(size_t)r1 * HD + col] = __float2half(acc1 * dinv[r1]);
}

// ---- head: out = (a2 + b2) @ Wc + bc   [N,64]x[64,16] ----
__global__ __launch_bounds__(256) void final_kernel(
    const float* __restrict__ ain, const float* __restrict__ b2,
    const float* __restrict__ Wc, const float* __restrict__ bc,
    float* __restrict__ out, int N) {
    __shared__ float Ws[HD * OD];     // 4 KB
    __shared__ float hs[16][HD + 1];  // padded
    int tid = threadIdx.x;
    for (int i = tid; i < HD * OD; i += 256) Ws[i] = Wc[i];
    int base = blockIdx.x * 16;
    for (int i = tid; i < 16 * HD; i += 256) {
        int r = i >> 6, c = i & 63;
        int row = base + r;
        hs[r][c] = (row < N) ? ain[(size_t)row * HD + c] + b2[c] : 0.0f;
    }
    __syncthreads();
    int col = tid & 15, r = tid >> 4;
    int row = base + r;
    if (row < N) {
        float acc = bc[col];
        #pragma unroll
        for (int k = 0; k < HD; ++k)
            acc += hs[r][k] * Ws[k * OD + col];
        out[(size_t)row * OD + col] = acc;
    }
}

extern "C" void kernel_launch(void* const* d_in, const int* in_sizes, int n_in,
                              void* d_out, int out_size, void* d_ws, size_t ws_size,
                              hipStream_t stream) {
    const float* x  = (const float*)d_in[0];
    const int*   ei = (const int*)d_in[1];   // [2,E] flat int32
    const float* W1 = (const float*)d_in[2];
    const float* b1 = (const float*)d_in[3];
    const float* W2 = (const float*)d_in[4];
    const float* b2 = (const float*)d_in[5];
    const float* Wc = (const float*)d_in[6];
    const float* bc = (const float*)d_in[7];
    float* out = (float*)d_out;

    int N = in_sizes[0] / ID;   // 100000
    int E = in_sizes[1] / 2;    // 1600000 (multiple of 4)
    const int* src = ei;
    const int* dst = ei + E;
    int K = (N + RB - 1) / RB;  // 196 coarse buckets (K <= KMAX)
    int Npad = (N + 63) & ~63;

    char* p = (char*)d_ws;
    int*      cnt    = (int*)p;      p += KMAX * 4;
    int*      coff   = (int*)p;      p += (KMAX + 4) * 4;
    int*      cursor = (int*)p;      p += KMAX * 4;
    float*    dinv   = (float*)p;    p += (size_t)Npad * 4;
    int*      off    = (int*)p;      p += (size_t)(Npad + RB) * 4;
    unsigned* epk    = (unsigned*)p; p += (size_t)E * 4;       // bucketed packed edges
    int*      sse    = (int*)p;      p += (size_t)E * 4;       // CSR src, dst-sorted
    __half*   th     = (__half*)p;   p += (size_t)N * HD * 2;  // dinv-premult msgs
    float*    a1     = (float*)p;    p += (size_t)N * HD * 4;  // agg out (reused)

    hipMemsetAsync(cnt, 0, (size_t)K * sizeof(int), stream);

    // dense CSR build (shared by both layers)
    passA_kernel<<<512, 256, 0, stream>>>((const int4*)dst, cnt, E / 4, K);
    cscan_kernel<<<1, KMAX, 0, stream>>>(cnt, coff, cursor, K, E);
    passB_kernel<<<(E + CHUNK - 1) / CHUNK, 256, 0, stream>>>(src, dst, cursor, epk, E);
    sortB_kernel<<<K, RB, 0, stream>>>(coff, epk, sse, off, dinv, N);

    // layer 1
    gemm1_kernel<<<(N + 7) / 8, 256, 0, stream>>>(x, W1, dinv, th, N);
    pull_kernel<<<(N * 64 + 255) / 256, 256, 0, stream>>>(off, sse, dinv, th, a1, N);

    // layer 2
    gemm2_kernel<<<(N + 7) / 8, 256, 0, stream>>>(a1, W2, b1, dinv, th, N);
    pull_kernel<<<(N * 64 + 255) / 256, 256, 0, stream>>>(off, sse, dinv, th, a1, N);

    // head
    final_kernel<<<(N + 15) / 16, 256, 0, stream>>>(a1, b2, Wc, bc, out, N);
}

// Round 8
// 330.392 us; speedup vs baseline: 6.1019x; 1.2102x over previous
//
#include <hip/hip_runtime.h>

// TemporalGCN: 2-layer GCN (gcn_norm, self-loops) + linear head.
// N=100000, E=1.6M, dims 128->64->64->16.
//
// R2: fp32-atomic push scatter = TCC atomic-rate bound (400MB WRITE/layer).
// R3: CSR+pull = 555us; bucket_kernel = scattered-4B-write bound (134us).
// R4: LDS-accumulate agg regressed 7x (wave-serial latency-exposed chain).
// R6: passB w/ 196..782 global cursors = atomic-contention bound (377us).
// R7: block-staged passB (LDS reorder + 1 atomic per chunk-bucket) = 400us
//     total; gemm1 (fp32 vector, LDS-issue bound, 74us) now dominates.
// R8: GEMMs -> fp16 MFMA (mfma_f32_16x16x32_f16, fp32 accum). K-permutation
//     invariance lets A/B fragments be contiguous b128 loads from [m][k] /
//     [n][k] LDS; XOR swizzle (halfidx ^= (row&7)<<3) kills the stride-256B
//     bank conflict; C/D layout col=lane&15,row=(lane>>4)*4+reg (m89).

constexpr int ID = 128;   // input dim
constexpr int HD = 64;    // hidden dim
constexpr int OD = 16;    // output dim
constexpr int RB = 512;   // nodes per coarse bucket
constexpr int KMAX = 256; // max buckets (K = ceil(N/RB) = 196)
constexpr int CHUNK = 4096;

typedef _Float16 f16x8 __attribute__((ext_vector_type(8)));
typedef float    f32x4 __attribute__((ext_vector_type(4)));

// ---- pass A: coarse histogram of dst>>9 ----
__global__ __launch_bounds__(256) void passA_kernel(const int4* __restrict__ dst4,
                                                    int* __restrict__ cnt, int E4, int K) {
    __shared__ int h[KMAX];
    int tid = threadIdx.x;
    for (int i = tid; i < K; i += 256) h[i] = 0;
    __syncthreads();
    int id = blockIdx.x * 256 + tid, n = gridDim.x * 256;
    for (int i = id; i < E4; i += n) {
        int4 d = dst4[i];
        atomicAdd(&h[d.x >> 9], 1); atomicAdd(&h[d.y >> 9], 1);
        atomicAdd(&h[d.z >> 9], 1); atomicAdd(&h[d.w >> 9], 1);
    }
    __syncthreads();
    for (int i = tid; i < K; i += 256) if (h[i]) atomicAdd(&cnt[i], h[i]);
}

// ---- coarse scan: cnt[K] -> coff[K+1] (exclusive), cursor[K] ----
__global__ __launch_bounds__(256) void cscan_kernel(const int* __restrict__ cnt,
                                                    int* __restrict__ coff,
                                                    int* __restrict__ cursor, int K, int E) {
    __shared__ int ts[KMAX];
    int tid = threadIdx.x;
    int v = (tid < K) ? cnt[tid] : 0;
    ts[tid] = v; __syncthreads();
    for (int d = 1; d < KMAX; d <<= 1) {
        int t = (tid >= d) ? ts[tid - d] : 0;
        __syncthreads();
        ts[tid] += t;
        __syncthreads();
    }
    if (tid < K) { int excl = ts[tid] - v; coff[tid] = excl; cursor[tid] = excl; }
    if (tid == 0) coff[K] = E;
}

// ---- pass B (block-staged): chunk -> LDS histogram -> one global atomicAdd
// per (chunk,bucket) -> LDS reorder -> bucket-grouped coalesced writeout.
__global__ __launch_bounds__(256) void passB_kernel(const int* __restrict__ src,
                                                    const int* __restrict__ dst,
                                                    int* __restrict__ cursor,
                                                    unsigned* __restrict__ epk, int E) {
    __shared__ unsigned      buf[CHUNK];      // 16 KB  reordered payloads
    __shared__ unsigned char bkt[CHUNK];      //  4 KB  bucket of each slot
    __shared__ int hist[KMAX], lofs[KMAX], gpos[KMAX], ts[KMAX];
    int tid = threadIdx.x;
    int base = blockIdx.x * CHUNK;
    int cnt = min(CHUNK, E - base);

    for (int i = tid; i < KMAX; i += 256) hist[i] = 0;
    __syncthreads();

    unsigned mypay[CHUNK / 256];
    short    myb[CHUNK / 256];
    short    myrank[CHUNK / 256];
    #pragma unroll
    for (int j = 0; j < CHUNK / 256; ++j) {
        int o = j * 256 + tid;
        myb[j] = -1;
        if (o < cnt) {
            int d = dst[base + o], s = src[base + o];
            int b = d >> 9;
            myb[j] = (short)b;
            myrank[j] = (short)atomicAdd(&hist[b], 1);
            mypay[j] = ((unsigned)(d & (RB - 1)) << 17) | (unsigned)s;
        }
    }
    __syncthreads();

    int v = hist[tid];
    ts[tid] = v; __syncthreads();
    for (int d = 1; d < KMAX; d <<= 1) {
        int t = (tid >= d) ? ts[tid - d] : 0;
        __syncthreads();
        ts[tid] += t;
        __syncthreads();
    }
    lofs[tid] = ts[tid] - v;
    if (v > 0) gpos[tid] = atomicAdd(&cursor[tid], v);
    __syncthreads();

    #pragma unroll
    for (int j = 0; j < CHUNK / 256; ++j) {
        if (myb[j] >= 0) {
            int pos = lofs[myb[j]] + myrank[j];
            buf[pos] = mypay[j];
            bkt[pos] = (unsigned char)myb[j];
        }
    }
    __syncthreads();

    for (int i = tid; i < cnt; i += 256) {
        int b = bkt[i];
        epk[gpos[b] + (i - lofs[b])] = buf[i];
    }
}

// ---- per-bucket sort -> exact CSR (off, sse) + dinv ----
__global__ __launch_bounds__(512) void sortB_kernel(
    const int* __restrict__ coff, const unsigned* __restrict__ epk,
    int* __restrict__ sse, int* __restrict__ off,
    float* __restrict__ dinv, int N) {
    __shared__ int hist[RB];
    __shared__ int lofs[RB];
    __shared__ int ts[RB];
    int b = blockIdx.x, tid = threadIdx.x, base = b * RB;
    hist[tid] = 0;
    __syncthreads();
    int e0 = coff[b], e1 = coff[b + 1];
    for (int e = e0 + tid; e < e1; e += 512)
        atomicAdd(&hist[epk[e] >> 17], 1);
    __syncthreads();
    int v = hist[tid];
    ts[tid] = v; __syncthreads();
    for (int d = 1; d < RB; d <<= 1) {
        int t = (tid >= d) ? ts[tid - d] : 0;
        __syncthreads();
        ts[tid] += t;
        __syncthreads();
    }
    {
        int excl = ts[tid] - v;
        int node = base + tid;
        if (node <= N) off[node] = e0 + excl;
        if (node < N)  dinv[node] = rsqrtf((float)v + 1.0f);
        lofs[tid] = e0 + excl;
    }
    __syncthreads();
    for (int e = e0 + tid; e < e1; e += 512) {
        unsigned pk = epk[e];
        int pos = atomicAdd(&lofs[pk >> 17], 1);
        sse[pos] = (int)(pk & 0x1FFFF);
    }
}

// ---- prep: transpose weights to fp16 [n][k] for MFMA B-operand ----
__global__ __launch_bounds__(256) void prep_kernel(const float* __restrict__ W1,
                                                   const float* __restrict__ W2,
                                                   _Float16* __restrict__ w1t,
                                                   _Float16* __restrict__ w2t) {
    int id = blockIdx.x * 256 + threadIdx.x, n = gridDim.x * 256;
    for (int i = id; i < ID * HD; i += n) {     // W1 [128][64] -> w1t [64][128]
        int k = i >> 6, c = i & 63;
        w1t[c * ID + k] = (_Float16)W1[i];
    }
    for (int i = id; i < HD * HD; i += n) {     // W2 [64][64] -> w2t [64][64]
        int k = i >> 6, c = i & 63;
        w2t[c * HD + k] = (_Float16)W2[i];
    }
}

// ---- GEMM1 (MFMA): th = fp16( (x @ W1) * dinv[row] )  [N,128]x[128,64] ----
__global__ __launch_bounds__(256) void gemm1_kernel(
    const float* __restrict__ x, const _Float16* __restrict__ w1t,
    const float* __restrict__ dinv, _Float16* __restrict__ th, int N) {
    __shared__ __align__(16) _Float16 xh[64 * ID];  // 16 KB, swizzled
    __shared__ __align__(16) _Float16 wh[HD * ID];  // 16 KB, swizzled
    int tid = threadIdx.x;
    int base = blockIdx.x * 64;
    // stage W (all blocks read the same 16KB -> L2 broadcast)
    #pragma unroll
    for (int it = 0; it < 4; ++it) {
        int idx = (it * 256 + tid) * 8;       // 0..8191 step 8
        int r = idx >> 7, c = idx & 127;
        f16x8 v = *(const f16x8*)&w1t[idx];
        *(f16x8*)&wh[r * ID + (c ^ ((r & 7) << 3))] = v;
    }
    // stage x rows (fp32 -> fp16, swizzled)
    #pragma unroll
    for (int it = 0; it < 4; ++it) {
        int idx = (it * 256 + tid) * 8;
        int r = idx >> 7, c = idx & 127;
        int row = base + r;
        f16x8 h;
        if (row < N) {
            float4 a = *(const float4*)&x[(size_t)row * ID + c];
            float4 b = *(const float4*)&x[(size_t)row * ID + c + 4];
            h[0] = (_Float16)a.x; h[1] = (_Float16)a.y;
            h[2] = (_Float16)a.z; h[3] = (_Float16)a.w;
            h[4] = (_Float16)b.x; h[5] = (_Float16)b.y;
            h[6] = (_Float16)b.z; h[7] = (_Float16)b.w;
        } else {
            #pragma unroll
            for (int j = 0; j < 8; ++j) h[j] = (_Float16)0.f;
        }
        *(f16x8*)&xh[r * ID + (c ^ ((r & 7) << 3))] = h;
    }
    __syncthreads();
    int lane = tid & 63, wv = tid >> 6;       // 4 waves; wave = 16 rows
    int lr = lane & 15, g = lane >> 4;
    f32x4 z = {0.f, 0.f, 0.f, 0.f};
    f32x4 acc[4] = {z, z, z, z};
    #pragma unroll
    for (int kk = 0; kk < 4; ++kk) {          // K = 128, 32 per step
        int kb = kk * 32 + g * 8;
        int ar = wv * 16 + lr;
        f16x8 af = *(const f16x8*)&xh[ar * ID + (kb ^ ((ar & 7) << 3))];
        #pragma unroll
        for (int ct = 0; ct < 4; ++ct) {
            int br = ct * 16 + lr;
            f16x8 bf = *(const f16x8*)&wh[br * ID + (kb ^ ((br & 7) << 3))];
            acc[ct] = __builtin_amdgcn_mfma_f32_16x16x32_f16(af, bf, acc[ct], 0, 0, 0);
        }
    }
    // epilogue: C/D layout col=lane&15, row=g*4+j (m89-verified)
    int r0 = base + wv * 16 + g * 4;
    #pragma unroll
    for (int j = 0; j < 4; ++j) {
        int row = r0 + j;
        if (row < N) {
            float dd = dinv[row];
            #pragma unroll
            for (int ct = 0; ct < 4; ++ct)
                th[(size_t)row * HD + ct * 16 + lr] = (_Float16)(acc[ct][j] * dd);
        }
    }
}

// ---- pull: one wave per node, lane = feature. th is dinv-premultiplied ----
__global__ __launch_bounds__(256) void pull_kernel(
    const int* __restrict__ off, const int* __restrict__ sse,
    const float* __restrict__ dinv, const _Float16* __restrict__ th,
    float* __restrict__ a, int N) {
    int lane = threadIdx.x & 63;
    int w = (blockIdx.x * blockDim.x + threadIdx.x) >> 6;
    if (w >= N) return;
    int o0 = off[w], o1 = off[w + 1];
    float acc = 0.f;
    int j = o0;
    for (; j + 7 < o1; j += 8) {
        int s0 = sse[j],   s1 = sse[j+1], s2 = sse[j+2], s3 = sse[j+3];
        int s4 = sse[j+4], s5 = sse[j+5], s6 = sse[j+6], s7 = sse[j+7];
        float t0 = (float)th[(size_t)s0 * HD + lane];
        float t1 = (float)th[(size_t)s1 * HD + lane];
        float t2 = (float)th[(size_t)s2 * HD + lane];
        float t3 = (float)th[(size_t)s3 * HD + lane];
        float t4 = (float)th[(size_t)s4 * HD + lane];
        float t5 = (float)th[(size_t)s5 * HD + lane];
        float t6 = (float)th[(size_t)s6 * HD + lane];
        float t7 = (float)th[(size_t)s7 * HD + lane];
        acc += ((t0 + t1) + (t2 + t3)) + ((t4 + t5) + (t6 + t7));
    }
    for (; j < o1; ++j)
        acc += (float)th[(size_t)sse[j] * HD + lane];
    a[(size_t)w * HD + lane] =
        dinv[w] * (acc + (float)th[(size_t)w * HD + lane]);
}

// ---- GEMM2 (MFMA): th = fp16( (relu(a1+b1) @ W2) * dinv[row] ) ----
__global__ __launch_bounds__(256) void gemm2_kernel(
    const float* __restrict__ ain, const _Float16* __restrict__ w2t,
    const float* __restrict__ bias, const float* __restrict__ dinv,
    _Float16* __restrict__ th, int N) {
    __shared__ __align__(16) _Float16 ah[64 * HD];  // 8 KB, swizzled
    __shared__ __align__(16) _Float16 wh[HD * HD];  // 8 KB, swizzled
    int tid = threadIdx.x;
    int base = blockIdx.x * 64;
    // stage W2t [64][64]
    #pragma unroll
    for (int it = 0; it < 2; ++it) {
        int idx = (it * 256 + tid) * 8;       // 0..4095 step 8
        int r = idx >> 6, c = idx & 63;
        f16x8 v = *(const f16x8*)&w2t[idx];
        *(f16x8*)&wh[r * HD + (c ^ ((r & 7) << 3))] = v;
    }
    // stage relu(a1+b1) -> fp16
    #pragma unroll
    for (int it = 0; it < 2; ++it) {
        int idx = (it * 256 + tid) * 8;
        int r = idx >> 6, c = idx & 63;
        int row = base + r;
        f16x8 h;
        if (row < N) {
            float4 a = *(const float4*)&ain[(size_t)row * HD + c];
            float4 b = *(const float4*)&ain[(size_t)row * HD + c + 4];
            h[0] = (_Float16)fmaxf(a.x + bias[c + 0], 0.f);
            h[1] = (_Float16)fmaxf(a.y + bias[c + 1], 0.f);
            h[2] = (_Float16)fmaxf(a.z + bias[c + 2], 0.f);
            h[3] = (_Float16)fmaxf(a.w + bias[c + 3], 0.f);
            h[4] = (_Float16)fmaxf(b.x + bias[c + 4], 0.f);
            h[5] = (_Float16)fmaxf(b.y + bias[c + 5], 0.f);
            h[6] = (_Float16)fmaxf(b.z + bias[c + 6], 0.f);
            h[7] = (_Float16)fmaxf(b.w + bias[c + 7], 0.f);
        } else {
            #pragma unroll
            for (int j = 0; j < 8; ++j) h[j] = (_Float16)0.f;
        }
        *(f16x8*)&ah[r * HD + (c ^ ((r & 7) << 3))] = h;
    }
    __syncthreads();
    int lane = tid & 63, wv = tid >> 6;
    int lr = lane & 15, g = lane >> 4;
    f32x4 z = {0.f, 0.f, 0.f, 0.f};
    f32x4 acc[4] = {z, z, z, z};
    #pragma unroll
    for (int kk = 0; kk < 2; ++kk) {          // K = 64, 32 per step
        int kb = kk * 32 + g * 8;
        int ar = wv * 16 + lr;
        f16x8 af = *(const f16x8*)&ah[ar * HD + (kb ^ ((ar & 7) << 3))];
        #pragma unroll
        for (int ct = 0; ct < 4; ++ct) {
            int br = ct * 16 + lr;
            f16x8 bf = *(const f16x8*)&wh[br * HD + (kb ^ ((br & 7) << 3))];
            acc[ct] = __builtin_amdgcn_mfma_f32_16x16x32_f16(af, bf, acc[ct], 0, 0, 0);
        }
    }
    int r0 = base + wv * 16 + g * 4;
    #pragma unroll
    for (int j = 0; j < 4; ++j) {
        int row = r0 + j;
        if (row < N) {
            float dd = dinv[row];
            #pragma unroll
            for (int ct = 0; ct < 4; ++ct)
                th[(size_t)row * HD + ct * 16 + lr] = (_Float16)(acc[ct][j] * dd);
        }
    }
}

// ---- head: out = (a2 + b2) @ Wc + bc   [N,64]x[64,16] ----
__global__ __launch_bounds__(256) void final_kernel(
    const float* __restrict__ ain, const float* __restrict__ b2,
    const float* __restrict__ Wc, const float* __restrict__ bc,
    float* __restrict__ out, int N) {
    __shared__ float Ws[HD * OD];     // 4 KB
    __shared__ float hs[16][HD + 1];  // padded
    int tid = threadIdx.x;
    for (int i = tid; i < HD * OD; i += 256) Ws[i] = Wc[i];
    int base = blockIdx.x * 16;
    for (int i = tid; i < 16 * HD; i += 256) {
        int r = i >> 6, c = i & 63;
        int row = base + r;
        hs[r][c] = (row < N) ? ain[(size_t)row * HD + c] + b2[c] : 0.0f;
    }
    __syncthreads();
    int col = tid & 15, r = tid >> 4;
    int row = base + r;
    if (row < N) {
        float acc = bc[col];
        #pragma unroll
        for (int k = 0; k < HD; ++k)
            acc += hs[r][k] * Ws[k * OD + col];
        out[(size_t)row * OD + col] = acc;
    }
}

extern "C" void kernel_launch(void* const* d_in, const int* in_sizes, int n_in,
                              void* d_out, int out_size, void* d_ws, size_t ws_size,
                              hipStream_t stream) {
    const float* x  = (const float*)d_in[0];
    const int*   ei = (const int*)d_in[1];   // [2,E] flat int32
    const float* W1 = (const float*)d_in[2];
    const float* b1 = (const float*)d_in[3];
    const float* W2 = (const float*)d_in[4];
    const float* b2 = (const float*)d_in[5];
    const float* Wc = (const float*)d_in[6];
    const float* bc = (const float*)d_in[7];
    float* out = (float*)d_out;

    int N = in_sizes[0] / ID;   // 100000
    int E = in_sizes[1] / 2;    // 1600000 (multiple of 4)
    const int* src = ei;
    const int* dst = ei + E;
    int K = (N + RB - 1) / RB;  // 196 coarse buckets (K <= KMAX)
    int Npad = (N + 63) & ~63;

    char* p = (char*)d_ws;
    int*      cnt    = (int*)p;      p += KMAX * 4;
    int*      coff   = (int*)p;      p += (KMAX + 4) * 4;
    int*      cursor = (int*)p;      p += KMAX * 4;
    float*    dinv   = (float*)p;    p += (size_t)Npad * 4;
    int*      off    = (int*)p;      p += (size_t)(Npad + RB) * 4;
    _Float16* w1t    = (_Float16*)p; p += (size_t)HD * ID * 2;  // [64][128]
    _Float16* w2t    = (_Float16*)p; p += (size_t)HD * HD * 2;  // [64][64]
    unsigned* epk    = (unsigned*)p; p += (size_t)E * 4;        // bucketed edges
    int*      sse    = (int*)p;      p += (size_t)E * 4;        // CSR src
    _Float16* th     = (_Float16*)p; p += (size_t)N * HD * 2;   // dinv-premult msgs
    float*    a1     = (float*)p;    p += (size_t)N * HD * 4;   // agg out (reused)

    hipMemsetAsync(cnt, 0, (size_t)K * sizeof(int), stream);

    // dense CSR build (shared by both layers) + weight prep
    passA_kernel<<<512, 256, 0, stream>>>((const int4*)dst, cnt, E / 4, K);
    prep_kernel<<<32, 256, 0, stream>>>(W1, W2, w1t, w2t);
    cscan_kernel<<<1, KMAX, 0, stream>>>(cnt, coff, cursor, K, E);
    passB_kernel<<<(E + CHUNK - 1) / CHUNK, 256, 0, stream>>>(src, dst, cursor, epk, E);
    sortB_kernel<<<K, RB, 0, stream>>>(coff, epk, sse, off, dinv, N);

    // layer 1
    gemm1_kernel<<<(N + 63) / 64, 256, 0, stream>>>(x, w1t, dinv, th, N);
    pull_kernel<<<(N * 64 + 255) / 256, 256, 0, stream>>>(off, sse, dinv, th, a1, N);

    // layer 2
    gemm2_kernel<<<(N + 63) / 64, 256, 0, stream>>>(a1, w2t, b1, dinv, th, N);
    pull_kernel<<<(N * 64 + 255) / 256, 256, 0, stream>>>(off, sse, dinv, th, a1, N);

    // head
    final_kernel<<<(N + 15) / 16, 256, 0, stream>>>(a1, b2, Wc, bc, out, N);
}

// Round 9
// 308.176 us; speedup vs baseline: 6.5418x; 1.0721x over previous
//
#include <hip/hip_runtime.h>

// TemporalGCN: 2-layer GCN (gcn_norm, self-loops) + linear head.
// N=100000, E=1.6M, dims 128->64->64->16.
//
// R2: fp32-atomic push scatter = TCC atomic-rate bound (400MB WRITE/layer).
// R3: CSR+pull = 555us; bucket_kernel = scattered-4B-write bound (134us).
// R4: LDS-accumulate agg regressed 7x (shfl->gather->LDS-atomic serial chain).
// R6: passB w/ few global cursors = atomic-contention bound (377us).
// R7: block-staged passB = 400us; fp32 vector gemm1 (LDS-issue bound) tops.
// R8: fp16 MFMA GEMMs (K-permutation-invariant b128 fragments, XOR swizzle)
//     = 330us; pull now tops (72us x2): per-8-edge chain = 8 uniform 4B
//     index loads -> wait -> 8 gathers = 2 latency rounds per group.
// R9: pull loads 64 indices in ONE coalesced lane-parallel load, broadcasts
//     via __shfl (v_readlane, register-only) -> all gathers of a node in
//     flight in a single latency round; kills 1.6M broadcast vmem requests.

constexpr int ID = 128;   // input dim
constexpr int HD = 64;    // hidden dim
constexpr int OD = 16;    // output dim
constexpr int RB = 512;   // nodes per coarse bucket
constexpr int KMAX = 256; // max buckets (K = ceil(N/RB) = 196)
constexpr int CHUNK = 4096;

typedef _Float16 f16x8 __attribute__((ext_vector_type(8)));
typedef float    f32x4 __attribute__((ext_vector_type(4)));

// ---- pass A: coarse histogram of dst>>9 ----
__global__ __launch_bounds__(256) void passA_kernel(const int4* __restrict__ dst4,
                                                    int* __restrict__ cnt, int E4, int K) {
    __shared__ int h[KMAX];
    int tid = threadIdx.x;
    for (int i = tid; i < K; i += 256) h[i] = 0;
    __syncthreads();
    int id = blockIdx.x * 256 + tid, n = gridDim.x * 256;
    for (int i = id; i < E4; i += n) {
        int4 d = dst4[i];
        atomicAdd(&h[d.x >> 9], 1); atomicAdd(&h[d.y >> 9], 1);
        atomicAdd(&h[d.z >> 9], 1); atomicAdd(&h[d.w >> 9], 1);
    }
    __syncthreads();
    for (int i = tid; i < K; i += 256) if (h[i]) atomicAdd(&cnt[i], h[i]);
}

// ---- coarse scan: cnt[K] -> coff[K+1] (exclusive), cursor[K] ----
__global__ __launch_bounds__(256) void cscan_kernel(const int* __restrict__ cnt,
                                                    int* __restrict__ coff,
                                                    int* __restrict__ cursor, int K, int E) {
    __shared__ int ts[KMAX];
    int tid = threadIdx.x;
    int v = (tid < K) ? cnt[tid] : 0;
    ts[tid] = v; __syncthreads();
    for (int d = 1; d < KMAX; d <<= 1) {
        int t = (tid >= d) ? ts[tid - d] : 0;
        __syncthreads();
        ts[tid] += t;
        __syncthreads();
    }
    if (tid < K) { int excl = ts[tid] - v; coff[tid] = excl; cursor[tid] = excl; }
    if (tid == 0) coff[K] = E;
}

// ---- pass B (block-staged): chunk -> LDS histogram -> one global atomicAdd
// per (chunk,bucket) -> LDS reorder -> bucket-grouped coalesced writeout.
__global__ __launch_bounds__(256) void passB_kernel(const int* __restrict__ src,
                                                    const int* __restrict__ dst,
                                                    int* __restrict__ cursor,
                                                    unsigned* __restrict__ epk, int E) {
    __shared__ unsigned      buf[CHUNK];      // 16 KB  reordered payloads
    __shared__ unsigned char bkt[CHUNK];      //  4 KB  bucket of each slot
    __shared__ int hist[KMAX], lofs[KMAX], gpos[KMAX], ts[KMAX];
    int tid = threadIdx.x;
    int base = blockIdx.x * CHUNK;
    int cnt = min(CHUNK, E - base);

    for (int i = tid; i < KMAX; i += 256) hist[i] = 0;
    __syncthreads();

    unsigned mypay[CHUNK / 256];
    short    myb[CHUNK / 256];
    short    myrank[CHUNK / 256];
    #pragma unroll
    for (int j = 0; j < CHUNK / 256; ++j) {
        int o = j * 256 + tid;
        myb[j] = -1;
        if (o < cnt) {
            int d = dst[base + o], s = src[base + o];
            int b = d >> 9;
            myb[j] = (short)b;
            myrank[j] = (short)atomicAdd(&hist[b], 1);
            mypay[j] = ((unsigned)(d & (RB - 1)) << 17) | (unsigned)s;
        }
    }
    __syncthreads();

    int v = hist[tid];
    ts[tid] = v; __syncthreads();
    for (int d = 1; d < KMAX; d <<= 1) {
        int t = (tid >= d) ? ts[tid - d] : 0;
        __syncthreads();
        ts[tid] += t;
        __syncthreads();
    }
    lofs[tid] = ts[tid] - v;
    if (v > 0) gpos[tid] = atomicAdd(&cursor[tid], v);
    __syncthreads();

    #pragma unroll
    for (int j = 0; j < CHUNK / 256; ++j) {
        if (myb[j] >= 0) {
            int pos = lofs[myb[j]] + myrank[j];
            buf[pos] = mypay[j];
            bkt[pos] = (unsigned char)myb[j];
        }
    }
    __syncthreads();

    for (int i = tid; i < cnt; i += 256) {
        int b = bkt[i];
        epk[gpos[b] + (i - lofs[b])] = buf[i];
    }
}

// ---- per-bucket sort -> exact CSR (off, sse) + dinv ----
__global__ __launch_bounds__(512) void sortB_kernel(
    const int* __restrict__ coff, const unsigned* __restrict__ epk,
    int* __restrict__ sse, int* __restrict__ off,
    float* __restrict__ dinv, int N) {
    __shared__ int hist[RB];
    __shared__ int lofs[RB];
    __shared__ int ts[RB];
    int b = blockIdx.x, tid = threadIdx.x, base = b * RB;
    hist[tid] = 0;
    __syncthreads();
    int e0 = coff[b], e1 = coff[b + 1];
    for (int e = e0 + tid; e < e1; e += 512)
        atomicAdd(&hist[epk[e] >> 17], 1);
    __syncthreads();
    int v = hist[tid];
    ts[tid] = v; __syncthreads();
    for (int d = 1; d < RB; d <<= 1) {
        int t = (tid >= d) ? ts[tid - d] : 0;
        __syncthreads();
        ts[tid] += t;
        __syncthreads();
    }
    {
        int excl = ts[tid] - v;
        int node = base + tid;
        if (node <= N) off[node] = e0 + excl;
        if (node < N)  dinv[node] = rsqrtf((float)v + 1.0f);
        lofs[tid] = e0 + excl;
    }
    __syncthreads();
    for (int e = e0 + tid; e < e1; e += 512) {
        unsigned pk = epk[e];
        int pos = atomicAdd(&lofs[pk >> 17], 1);
        sse[pos] = (int)(pk & 0x1FFFF);
    }
}

// ---- prep: transpose weights to fp16 [n][k] for MFMA B-operand ----
__global__ __launch_bounds__(256) void prep_kernel(const float* __restrict__ W1,
                                                   const float* __restrict__ W2,
                                                   _Float16* __restrict__ w1t,
                                                   _Float16* __restrict__ w2t) {
    int id = blockIdx.x * 256 + threadIdx.x, n = gridDim.x * 256;
    for (int i = id; i < ID * HD; i += n) {     // W1 [128][64] -> w1t [64][128]
        int k = i >> 6, c = i & 63;
        w1t[c * ID + k] = (_Float16)W1[i];
    }
    for (int i = id; i < HD * HD; i += n) {     // W2 [64][64] -> w2t [64][64]
        int k = i >> 6, c = i & 63;
        w2t[c * HD + k] = (_Float16)W2[i];
    }
}

// ---- GEMM1 (MFMA): th = fp16( (x @ W1) * dinv[row] )  [N,128]x[128,64] ----
__global__ __launch_bounds__(256) void gemm1_kernel(
    const float* __restrict__ x, const _Float16* __restrict__ w1t,
    const float* __restrict__ dinv, _Float16* __restrict__ th, int N) {
    __shared__ __align__(16) _Float16 xh[64 * ID];  // 16 KB, swizzled
    __shared__ __align__(16) _Float16 wh[HD * ID];  // 16 KB, swizzled
    int tid = threadIdx.x;
    int base = blockIdx.x * 64;
    #pragma unroll
    for (int it = 0; it < 4; ++it) {
        int idx = (it * 256 + tid) * 8;       // 0..8191 step 8
        int r = idx >> 7, c = idx & 127;
        f16x8 v = *(const f16x8*)&w1t[idx];
        *(f16x8*)&wh[r * ID + (c ^ ((r & 7) << 3))] = v;
    }
    #pragma unroll
    for (int it = 0; it < 4; ++it) {
        int idx = (it * 256 + tid) * 8;
        int r = idx >> 7, c = idx & 127;
        int row = base + r;
        f16x8 h;
        if (row < N) {
            float4 a = *(const float4*)&x[(size_t)row * ID + c];
            float4 b = *(const float4*)&x[(size_t)row * ID + c + 4];
            h[0] = (_Float16)a.x; h[1] = (_Float16)a.y;
            h[2] = (_Float16)a.z; h[3] = (_Float16)a.w;
            h[4] = (_Float16)b.x; h[5] = (_Float16)b.y;
            h[6] = (_Float16)b.z; h[7] = (_Float16)b.w;
        } else {
            #pragma unroll
            for (int j = 0; j < 8; ++j) h[j] = (_Float16)0.f;
        }
        *(f16x8*)&xh[r * ID + (c ^ ((r & 7) << 3))] = h;
    }
    __syncthreads();
    int lane = tid & 63, wv = tid >> 6;       // 4 waves; wave = 16 rows
    int lr = lane & 15, g = lane >> 4;
    f32x4 z = {0.f, 0.f, 0.f, 0.f};
    f32x4 acc[4] = {z, z, z, z};
    #pragma unroll
    for (int kk = 0; kk < 4; ++kk) {          // K = 128, 32 per step
        int kb = kk * 32 + g * 8;
        int ar = wv * 16 + lr;
        f16x8 af = *(const f16x8*)&xh[ar * ID + (kb ^ ((ar & 7) << 3))];
        #pragma unroll
        for (int ct = 0; ct < 4; ++ct) {
            int br = ct * 16 + lr;
            f16x8 bf = *(const f16x8*)&wh[br * ID + (kb ^ ((br & 7) << 3))];
            acc[ct] = __builtin_amdgcn_mfma_f32_16x16x32_f16(af, bf, acc[ct], 0, 0, 0);
        }
    }
    int r0 = base + wv * 16 + g * 4;
    #pragma unroll
    for (int j = 0; j < 4; ++j) {
        int row = r0 + j;
        if (row < N) {
            float dd = dinv[row];
            #pragma unroll
            for (int ct = 0; ct < 4; ++ct)
                th[(size_t)row * HD + ct * 16 + lr] = (_Float16)(acc[ct][j] * dd);
        }
    }
}

// ---- pull: one wave per node, lane = feature. th is dinv-premultiplied:
// a[d] = dinv[d] * ( sum_{s in N(d)} th'[s] + th'[d] )
// Indices loaded 64-at-a-time lane-parallel, broadcast via __shfl
// (v_readlane) so all of a node's gathers issue in one latency round.
__global__ __launch_bounds__(256) void pull_kernel(
    const int* __restrict__ off, const int* __restrict__ sse,
    const float* __restrict__ dinv, const _Float16* __restrict__ th,
    float* __restrict__ a, int N) {
    int lane = threadIdx.x & 63;
    int w = (blockIdx.x * blockDim.x + threadIdx.x) >> 6;
    if (w >= N) return;
    int o0 = off[w], o1 = off[w + 1];
    float acc = 0.f;
    int j = o0;
    while (j < o1) {
        int nb = min(64, o1 - j);
        int sidx = (lane < nb) ? sse[j + lane] : 0;   // one coalesced 256B load
        int i = 0;
        for (; i + 7 < nb; i += 8) {
            int s0 = __shfl(sidx, i + 0), s1 = __shfl(sidx, i + 1);
            int s2 = __shfl(sidx, i + 2), s3 = __shfl(sidx, i + 3);
            int s4 = __shfl(sidx, i + 4), s5 = __shfl(sidx, i + 5);
            int s6 = __shfl(sidx, i + 6), s7 = __shfl(sidx, i + 7);
            float t0 = (float)th[(size_t)s0 * HD + lane];
            float t1 = (float)th[(size_t)s1 * HD + lane];
            float t2 = (float)th[(size_t)s2 * HD + lane];
            float t3 = (float)th[(size_t)s3 * HD + lane];
            float t4 = (float)th[(size_t)s4 * HD + lane];
            float t5 = (float)th[(size_t)s5 * HD + lane];
            float t6 = (float)th[(size_t)s6 * HD + lane];
            float t7 = (float)th[(size_t)s7 * HD + lane];
            acc += ((t0 + t1) + (t2 + t3)) + ((t4 + t5) + (t6 + t7));
        }
        for (; i < nb; ++i) {
            int s = __shfl(sidx, i);
            acc += (float)th[(size_t)s * HD + lane];
        }
        j += nb;
    }
    a[(size_t)w * HD + lane] =
        dinv[w] * (acc + (float)th[(size_t)w * HD + lane]);
}

// ---- GEMM2 (MFMA): th = fp16( (relu(a1+b1) @ W2) * dinv[row] ) ----
__global__ __launch_bounds__(256) void gemm2_kernel(
    const float* __restrict__ ain, const _Float16* __restrict__ w2t,
    const float* __restrict__ bias, const float* __restrict__ dinv,
    _Float16* __restrict__ th, int N) {
    __shared__ __align__(16) _Float16 ah[64 * HD];  // 8 KB, swizzled
    __shared__ __align__(16) _Float16 wh[HD * HD];  // 8 KB, swizzled
    int tid = threadIdx.x;
    int base = blockIdx.x * 64;
    #pragma unroll
    for (int it = 0; it < 2; ++it) {
        int idx = (it * 256 + tid) * 8;       // 0..4095 step 8
        int r = idx >> 6, c = idx & 63;
        f16x8 v = *(const f16x8*)&w2t[idx];
        *(f16x8*)&wh[r * HD + (c ^ ((r & 7) << 3))] = v;
    }
    #pragma unroll
    for (int it = 0; it < 2; ++it) {
        int idx = (it * 256 + tid) * 8;
        int r = idx >> 6, c = idx & 63;
        int row = base + r;
        f16x8 h;
        if (row < N) {
            float4 a = *(const float4*)&ain[(size_t)row * HD + c];
            float4 b = *(const float4*)&ain[(size_t)row * HD + c + 4];
            h[0] = (_Float16)fmaxf(a.x + bias[c + 0], 0.f);
            h[1] = (_Float16)fmaxf(a.y + bias[c + 1], 0.f);
            h[2] = (_Float16)fmaxf(a.z + bias[c + 2], 0.f);
            h[3] = (_Float16)fmaxf(a.w + bias[c + 3], 0.f);
            h[4] = (_Float16)fmaxf(b.x + bias[c + 4], 0.f);
            h[5] = (_Float16)fmaxf(b.y + bias[c + 5], 0.f);
            h[6] = (_Float16)fmaxf(b.z + bias[c + 6], 0.f);
            h[7] = (_Float16)fmaxf(b.w + bias[c + 7], 0.f);
        } else {
            #pragma unroll
            for (int j = 0; j < 8; ++j) h[j] = (_Float16)0.f;
        }
        *(f16x8*)&ah[r * HD + (c ^ ((r & 7) << 3))] = h;
    }
    __syncthreads();
    int lane = tid & 63, wv = tid >> 6;
    int lr = lane & 15, g = lane >> 4;
    f32x4 z = {0.f, 0.f, 0.f, 0.f};
    f32x4 acc[4] = {z, z, z, z};
    #pragma unroll
    for (int kk = 0; kk < 2; ++kk) {          // K = 64, 32 per step
        int kb = kk * 32 + g * 8;
        int ar = wv * 16 + lr;
        f16x8 af = *(const f16x8*)&ah[ar * HD + (kb ^ ((ar & 7) << 3))];
        #pragma unroll
        for (int ct = 0; ct < 4; ++ct) {
            int br = ct * 16 + lr;
            f16x8 bf = *(const f16x8*)&wh[br * HD + (kb ^ ((br & 7) << 3))];
            acc[ct] = __builtin_amdgcn_mfma_f32_16x16x32_f16(af, bf, acc[ct], 0, 0, 0);
        }
    }
    int r0 = base + wv * 16 + g * 4;
    #pragma unroll
    for (int j = 0; j < 4; ++j) {
        int row = r0 + j;
        if (row < N) {
            float dd = dinv[row];
            #pragma unroll
            for (int ct = 0; ct < 4; ++ct)
                th[(size_t)row * HD + ct * 16 + lr] = (_Float16)(acc[ct][j] * dd);
        }
    }
}

// ---- head: out = (a2 + b2) @ Wc + bc   [N,64]x[64,16] ----
__global__ __launch_bounds__(256) void final_kernel(
    const float* __restrict__ ain, const float* __restrict__ b2,
    const float* __restrict__ Wc, const float* __restrict__ bc,
    float* __restrict__ out, int N) {
    __shared__ float Ws[HD * OD];     // 4 KB
    __shared__ float hs[16][HD + 1];  // padded
    int tid = threadIdx.x;
    for (int i = tid; i < HD * OD; i += 256) Ws[i] = Wc[i];
    int base = blockIdx.x * 16;
    for (int i = tid; i < 16 * HD; i += 256) {
        int r = i >> 6, c = i & 63;
        int row = base + r;
        hs[r][c] = (row < N) ? ain[(size_t)row * HD + c] + b2[c] : 0.0f;
    }
    __syncthreads();
    int col = tid & 15, r = tid >> 4;
    int row = base + r;
    if (row < N) {
        float acc = bc[col];
        #pragma unroll
        for (int k = 0; k < HD; ++k)
            acc += hs[r][k] * Ws[k * OD + col];
        out[(size_t)row * OD + col] = acc;
    }
}

extern "C" void kernel_launch(void* const* d_in, const int* in_sizes, int n_in,
                              void* d_out, int out_size, void* d_ws, size_t ws_size,
                              hipStream_t stream) {
    const float* x  = (const float*)d_in[0];
    const int*   ei = (const int*)d_in[1];   // [2,E] flat int32
    const float* W1 = (const float*)d_in[2];
    const float* b1 = (const float*)d_in[3];
    const float* W2 = (const float*)d_in[4];
    const float* b2 = (const float*)d_in[5];
    const float* Wc = (const float*)d_in[6];
    const float* bc = (const float*)d_in[7];
    float* out = (float*)d_out;

    int N = in_sizes[0] / ID;   // 100000
    int E = in_sizes[1] / 2;    // 1600000 (multiple of 4)
    const int* src = ei;
    const int* dst = ei + E;
    int K = (N + RB - 1) / RB;  // 196 coarse buckets (K <= KMAX)
    int Npad = (N + 63) & ~63;

    char* p = (char*)d_ws;
    int*      cnt    = (int*)p;      p += KMAX * 4;
    int*      coff   = (int*)p;      p += (KMAX + 4) * 4;
    int*      cursor = (int*)p;      p += KMAX * 4;
    float*    dinv   = (float*)p;    p += (size_t)Npad * 4;
    int*      off    = (int*)p;      p += (size_t)(Npad + RB) * 4;
    _Float16* w1t    = (_Float16*)p; p += (size_t)HD * ID * 2;  // [64][128]
    _Float16* w2t    = (_Float16*)p; p += (size_t)HD * HD * 2;  // [64][64]
    unsigned* epk    = (unsigned*)p; p += (size_t)E * 4;        // bucketed edges
    int*      sse    = (int*)p;      p += (size_t)E * 4;        // CSR src
    _Float16* th     = (_Float16*)p; p += (size_t)N * HD * 2;   // dinv-premult msgs
    float*    a1     = (float*)p;    p += (size_t)N * HD * 4;   // agg out (reused)

    hipMemsetAsync(cnt, 0, (size_t)K * sizeof(int), stream);

    // dense CSR build (shared by both layers) + weight prep
    passA_kernel<<<512, 256, 0, stream>>>((const int4*)dst, cnt, E / 4, K);
    prep_kernel<<<32, 256, 0, stream>>>(W1, W2, w1t, w2t);
    cscan_kernel<<<1, KMAX, 0, stream>>>(cnt, coff, cursor, K, E);
    passB_kernel<<<(E + CHUNK - 1) / CHUNK, 256, 0, stream>>>(src, dst, cursor, epk, E);
    sortB_kernel<<<K, RB, 0, stream>>>(coff, epk, sse, off, dinv, N);

    // layer 1
    gemm1_kernel<<<(N + 63) / 64, 256, 0, stream>>>(x, w1t, dinv, th, N);
    pull_kernel<<<(N * 64 + 255) / 256, 256, 0, stream>>>(off, sse, dinv, th, a1, N);

    // layer 2
    gemm2_kernel<<<(N + 63) / 64, 256, 0, stream>>>(a1, w2t, b1, dinv, th, N);
    pull_kernel<<<(N * 64 + 255) / 256, 256, 0, stream>>>(off, sse, dinv, th, a1, N);

    // head
    final_kernel<<<(N + 15) / 16, 256, 0, stream>>>(a1, b2, Wc, bc, out, N);
}

// Round 10
// 294.351 us; speedup vs baseline: 6.8490x; 1.0470x over previous
//
#include <hip/hip_runtime.h>

// TemporalGCN: 2-layer GCN (gcn_norm, self-loops) + linear head.
// N=100000, E=1.6M, dims 128->64->64->16.
//
// R2: fp32-atomic push scatter = TCC atomic-rate bound (400MB WRITE/layer).
// R3: CSR+pull = 555us; bucket_kernel = scattered-4B-write bound (134us).
// R4: LDS-accumulate agg regressed 7x (shfl->gather->LDS-atomic serial chain).
// R6: passB w/ few global cursors = atomic-contention bound (377us).
// R7: block-staged passB = 400us; fp32 vector gemm1 (LDS-issue bound) tops.
// R8: fp16 MFMA GEMMs = 330us; pull tops (72us x2, index-load latency round).
// R9: shfl-broadcast indices = 308us; pull 59.6us each. Model: 23cyc/gather/CU
//     vs ~8 ideal -> bound by outstanding-load concurrency per CU, not BW
//     (L2 miss 77%, L3-served at 3.2TB/s effective).
// R10: 4 edges per wave-load: 16 lanes x 8B (f16x4) per edge row; each
//      outstanding load carries 4 edges (vmem instrs /4). Combine via
//      shfl_xor(16|32); lanes 0-15 write float4. Null result here would
//      mean per-CU miss concurrency / L3 random throughput = roofline.

constexpr int ID = 128;   // input dim
constexpr int HD = 64;    // hidden dim
constexpr int OD = 16;    // output dim
constexpr int RB = 512;   // nodes per coarse bucket
constexpr int KMAX = 256; // max buckets (K = ceil(N/RB) = 196)
constexpr int CHUNK = 4096;

typedef _Float16 f16x8 __attribute__((ext_vector_type(8)));
typedef _Float16 f16x4 __attribute__((ext_vector_type(4)));
typedef float    f32x4 __attribute__((ext_vector_type(4)));

// ---- pass A: coarse histogram of dst>>9 ----
__global__ __launch_bounds__(256) void passA_kernel(const int4* __restrict__ dst4,
                                                    int* __restrict__ cnt, int E4, int K) {
    __shared__ int h[KMAX];
    int tid = threadIdx.x;
    for (int i = tid; i < K; i += 256) h[i] = 0;
    __syncthreads();
    int id = blockIdx.x * 256 + tid, n = gridDim.x * 256;
    for (int i = id; i < E4; i += n) {
        int4 d = dst4[i];
        atomicAdd(&h[d.x >> 9], 1); atomicAdd(&h[d.y >> 9], 1);
        atomicAdd(&h[d.z >> 9], 1); atomicAdd(&h[d.w >> 9], 1);
    }
    __syncthreads();
    for (int i = tid; i < K; i += 256) if (h[i]) atomicAdd(&cnt[i], h[i]);
}

// ---- coarse scan: cnt[K] -> coff[K+1] (exclusive), cursor[K] ----
__global__ __launch_bounds__(256) void cscan_kernel(const int* __restrict__ cnt,
                                                    int* __restrict__ coff,
                                                    int* __restrict__ cursor, int K, int E) {
    __shared__ int ts[KMAX];
    int tid = threadIdx.x;
    int v = (tid < K) ? cnt[tid] : 0;
    ts[tid] = v; __syncthreads();
    for (int d = 1; d < KMAX; d <<= 1) {
        int t = (tid >= d) ? ts[tid - d] : 0;
        __syncthreads();
        ts[tid] += t;
        __syncthreads();
    }
    if (tid < K) { int excl = ts[tid] - v; coff[tid] = excl; cursor[tid] = excl; }
    if (tid == 0) coff[K] = E;
}

// ---- pass B (block-staged): chunk -> LDS histogram -> one global atomicAdd
// per (chunk,bucket) -> LDS reorder -> bucket-grouped coalesced writeout.
__global__ __launch_bounds__(256) void passB_kernel(const int* __restrict__ src,
                                                    const int* __restrict__ dst,
                                                    int* __restrict__ cursor,
                                                    unsigned* __restrict__ epk, int E) {
    __shared__ unsigned      buf[CHUNK];      // 16 KB  reordered payloads
    __shared__ unsigned char bkt[CHUNK];      //  4 KB  bucket of each slot
    __shared__ int hist[KMAX], lofs[KMAX], gpos[KMAX], ts[KMAX];
    int tid = threadIdx.x;
    int base = blockIdx.x * CHUNK;
    int cnt = min(CHUNK, E - base);

    for (int i = tid; i < KMAX; i += 256) hist[i] = 0;
    __syncthreads();

    unsigned mypay[CHUNK / 256];
    short    myb[CHUNK / 256];
    short    myrank[CHUNK / 256];
    #pragma unroll
    for (int j = 0; j < CHUNK / 256; ++j) {
        int o = j * 256 + tid;
        myb[j] = -1;
        if (o < cnt) {
            int d = dst[base + o], s = src[base + o];
            int b = d >> 9;
            myb[j] = (short)b;
            myrank[j] = (short)atomicAdd(&hist[b], 1);
            mypay[j] = ((unsigned)(d & (RB - 1)) << 17) | (unsigned)s;
        }
    }
    __syncthreads();

    int v = hist[tid];
    ts[tid] = v; __syncthreads();
    for (int d = 1; d < KMAX; d <<= 1) {
        int t = (tid >= d) ? ts[tid - d] : 0;
        __syncthreads();
        ts[tid] += t;
        __syncthreads();
    }
    lofs[tid] = ts[tid] - v;
    if (v > 0) gpos[tid] = atomicAdd(&cursor[tid], v);
    __syncthreads();

    #pragma unroll
    for (int j = 0; j < CHUNK / 256; ++j) {
        if (myb[j] >= 0) {
            int pos = lofs[myb[j]] + myrank[j];
            buf[pos] = mypay[j];
            bkt[pos] = (unsigned char)myb[j];
        }
    }
    __syncthreads();

    for (int i = tid; i < cnt; i += 256) {
        int b = bkt[i];
        epk[gpos[b] + (i - lofs[b])] = buf[i];
    }
}

// ---- per-bucket sort -> exact CSR (off, sse) + dinv ----
__global__ __launch_bounds__(512) void sortB_kernel(
    const int* __restrict__ coff, const unsigned* __restrict__ epk,
    int* __restrict__ sse, int* __restrict__ off,
    float* __restrict__ dinv, int N) {
    __shared__ int hist[RB];
    __shared__ int lofs[RB];
    __shared__ int ts[RB];
    int b = blockIdx.x, tid = threadIdx.x, base = b * RB;
    hist[tid] = 0;
    __syncthreads();
    int e0 = coff[b], e1 = coff[b + 1];
    for (int e = e0 + tid; e < e1; e += 512)
        atomicAdd(&hist[epk[e] >> 17], 1);
    __syncthreads();
    int v = hist[tid];
    ts[tid] = v; __syncthreads();
    for (int d = 1; d < RB; d <<= 1) {
        int t = (tid >= d) ? ts[tid - d] : 0;
        __syncthreads();
        ts[tid] += t;
        __syncthreads();
    }
    {
        int excl = ts[tid] - v;
        int node = base + tid;
        if (node <= N) off[node] = e0 + excl;
        if (node < N)  dinv[node] = rsqrtf((float)v + 1.0f);
        lofs[tid] = e0 + excl;
    }
    __syncthreads();
    for (int e = e0 + tid; e < e1; e += 512) {
        unsigned pk = epk[e];
        int pos = atomicAdd(&lofs[pk >> 17], 1);
        sse[pos] = (int)(pk & 0x1FFFF);
    }
}

// ---- prep: transpose weights to fp16 [n][k] for MFMA B-operand ----
__global__ __launch_bounds__(256) void prep_kernel(const float* __restrict__ W1,
                                                   const float* __restrict__ W2,
                                                   _Float16* __restrict__ w1t,
                                                   _Float16* __restrict__ w2t) {
    int id = blockIdx.x * 256 + threadIdx.x, n = gridDim.x * 256;
    for (int i = id; i < ID * HD; i += n) {     // W1 [128][64] -> w1t [64][128]
        int k = i >> 6, c = i & 63;
        w1t[c * ID + k] = (_Float16)W1[i];
    }
    for (int i = id; i < HD * HD; i += n) {     // W2 [64][64] -> w2t [64][64]
        int k = i >> 6, c = i & 63;
        w2t[c * HD + k] = (_Float16)W2[i];
    }
}

// ---- GEMM1 (MFMA): th = fp16( (x @ W1) * dinv[row] )  [N,128]x[128,64] ----
__global__ __launch_bounds__(256) void gemm1_kernel(
    const float* __restrict__ x, const _Float16* __restrict__ w1t,
    const float* __restrict__ dinv, _Float16* __restrict__ th, int N) {
    __shared__ __align__(16) _Float16 xh[64 * ID];  // 16 KB, swizzled
    __shared__ __align__(16) _Float16 wh[HD * ID];  // 16 KB, swizzled
    int tid = threadIdx.x;
    int base = blockIdx.x * 64;
    #pragma unroll
    for (int it = 0; it < 4; ++it) {
        int idx = (it * 256 + tid) * 8;       // 0..8191 step 8
        int r = idx >> 7, c = idx & 127;
        f16x8 v = *(const f16x8*)&w1t[idx];
        *(f16x8*)&wh[r * ID + (c ^ ((r & 7) << 3))] = v;
    }
    #pragma unroll
    for (int it = 0; it < 4; ++it) {
        int idx = (it * 256 + tid) * 8;
        int r = idx >> 7, c = idx & 127;
        int row = base + r;
        f16x8 h;
        if (row < N) {
            float4 a = *(const float4*)&x[(size_t)row * ID + c];
            float4 b = *(const float4*)&x[(size_t)row * ID + c + 4];
            h[0] = (_Float16)a.x; h[1] = (_Float16)a.y;
            h[2] = (_Float16)a.z; h[3] = (_Float16)a.w;
            h[4] = (_Float16)b.x; h[5] = (_Float16)b.y;
            h[6] = (_Float16)b.z; h[7] = (_Float16)b.w;
        } else {
            #pragma unroll
            for (int j = 0; j < 8; ++j) h[j] = (_Float16)0.f;
        }
        *(f16x8*)&xh[r * ID + (c ^ ((r & 7) << 3))] = h;
    }
    __syncthreads();
    int lane = tid & 63, wv = tid >> 6;       // 4 waves; wave = 16 rows
    int lr = lane & 15, g = lane >> 4;
    f32x4 z = {0.f, 0.f, 0.f, 0.f};
    f32x4 acc[4] = {z, z, z, z};
    #pragma unroll
    for (int kk = 0; kk < 4; ++kk) {          // K = 128, 32 per step
        int kb = kk * 32 + g * 8;
        int ar = wv * 16 + lr;
        f16x8 af = *(const f16x8*)&xh[ar * ID + (kb ^ ((ar & 7) << 3))];
        #pragma unroll
        for (int ct = 0; ct < 4; ++ct) {
            int br = ct * 16 + lr;
            f16x8 bf = *(const f16x8*)&wh[br * ID + (kb ^ ((br & 7) << 3))];
            acc[ct] = __builtin_amdgcn_mfma_f32_16x16x32_f16(af, bf, acc[ct], 0, 0, 0);
        }
    }
    int r0 = base + wv * 16 + g * 4;
    #pragma unroll
    for (int j = 0; j < 4; ++j) {
        int row = r0 + j;
        if (row < N) {
            float dd = dinv[row];
            #pragma unroll
            for (int ct = 0; ct < 4; ++ct)
                th[(size_t)row * HD + ct * 16 + lr] = (_Float16)(acc[ct][j] * dd);
        }
    }
}

// ---- pull: one wave per node; 4 edges per wave-load (16 lanes x 8B each).
// th is dinv-premultiplied: a[d] = dinv[d] * ( sum_{s in N(d)} th'[s] + th'[d] )
// sub = edge slot (0..3) within a load quad; fl = feature quad (features
// 4fl..4fl+3). Combine sub-partials with shfl_xor(16|32); lanes 0-15 write.
__global__ __launch_bounds__(256) void pull_kernel(
    const int* __restrict__ off, const int* __restrict__ sse,
    const float* __restrict__ dinv, const _Float16* __restrict__ th,
    float* __restrict__ a, int N) {
    int lane = threadIdx.x & 63;
    int w = (blockIdx.x * blockDim.x + threadIdx.x) >> 6;
    if (w >= N) return;
    int sub = lane >> 4;        // 0..3: which edge of the quad
    int fl  = lane & 15;        // feature-quad index
    const f16x4* th4 = (const f16x4*)th;    // row = 16 x f16x4
    int o0 = off[w], o1 = off[w + 1];
    float ax = 0.f, ay = 0.f, az = 0.f, aw = 0.f;
    int j = o0;
    while (j < o1) {
        int nb = min(64, o1 - j);
        int sidx = (lane < nb) ? sse[j + lane] : 0;   // one coalesced load
        int i = 0;
        for (; i + 15 < nb; i += 16) {                // 16 edges / iter, 4 loads
            int s0 = __shfl(sidx, i + sub);
            int s1 = __shfl(sidx, i + 4 + sub);
            int s2 = __shfl(sidx, i + 8 + sub);
            int s3 = __shfl(sidx, i + 12 + sub);
            f16x4 v0 = th4[(size_t)s0 * 16 + fl];
            f16x4 v1 = th4[(size_t)s1 * 16 + fl];
            f16x4 v2 = th4[(size_t)s2 * 16 + fl];
            f16x4 v3 = th4[(size_t)s3 * 16 + fl];
            ax += ((float)v0[0] + (float)v1[0]) + ((float)v2[0] + (float)v3[0]);
            ay += ((float)v0[1] + (float)v1[1]) + ((float)v2[1] + (float)v3[1]);
            az += ((float)v0[2] + (float)v1[2]) + ((float)v2[2] + (float)v3[2]);
            aw += ((float)v0[3] + (float)v1[3]) + ((float)v2[3] + (float)v3[3]);
        }
        for (; i < nb; i += 4) {                      // tail quads (predicated)
            int e = i + sub;
            int s = __shfl(sidx, (e < nb) ? e : (nb - 1));
            if (e < nb) {
                f16x4 v = th4[(size_t)s * 16 + fl];
                ax += (float)v[0]; ay += (float)v[1];
                az += (float)v[2]; aw += (float)v[3];
            }
        }
        j += nb;
    }
    // combine the 4 sub-group partials (lanes fl, fl+16, fl+32, fl+48)
    ax += __shfl_xor(ax, 16); ax += __shfl_xor(ax, 32);
    ay += __shfl_xor(ay, 16); ay += __shfl_xor(ay, 32);
    az += __shfl_xor(az, 16); az += __shfl_xor(az, 32);
    aw += __shfl_xor(aw, 16); aw += __shfl_xor(aw, 32);
    if (sub == 0) {
        f16x4 sv = th4[(size_t)w * 16 + fl];          // self-term (coalesced)
        float dd = dinv[w];
        float4 o;
        o.x = dd * (ax + (float)sv[0]);
        o.y = dd * (ay + (float)sv[1]);
        o.z = dd * (az + (float)sv[2]);
        o.w = dd * (aw + (float)sv[3]);
        *(float4*)&a[(size_t)w * HD + fl * 4] = o;    // 16 lanes x 16B = 256B
    }
}

// ---- GEMM2 (MFMA): th = fp16( (relu(a1+b1) @ W2) * dinv[row] ) ----
__global__ __launch_bounds__(256) void gemm2_kernel(
    const float* __restrict__ ain, const _Float16* __restrict__ w2t,
    const float* __restrict__ bias, const float* __restrict__ dinv,
    _Float16* __restrict__ th, int N) {
    __shared__ __align__(16) _Float16 ah[64 * HD];  // 8 KB, swizzled
    __shared__ __align__(16) _Float16 wh[HD * HD];  // 8 KB, swizzled
    int tid = threadIdx.x;
    int base = blockIdx.x * 64;
    #pragma unroll
    for (int it = 0; it < 2; ++it) {
        int idx = (it * 256 + tid) * 8;       // 0..4095 step 8
        int r = idx >> 6, c = idx & 63;
        f16x8 v = *(const f16x8*)&w2t[idx];
        *(f16x8*)&wh[r * HD + (c ^ ((r & 7) << 3))] = v;
    }
    #pragma unroll
    for (int it = 0; it < 2; ++it) {
        int idx = (it * 256 + tid) * 8;
        int r = idx >> 6, c = idx & 63;
        int row = base + r;
        f16x8 h;
        if (row < N) {
            float4 a = *(const float4*)&ain[(size_t)row * HD + c];
            float4 b = *(const float4*)&ain[(size_t)row * HD + c + 4];
            h[0] = (_Float16)fmaxf(a.x + bias[c + 0], 0.f);
            h[1] = (_Float16)fmaxf(a.y + bias[c + 1], 0.f);
            h[2] = (_Float16)fmaxf(a.z + bias[c + 2], 0.f);
            h[3] = (_Float16)fmaxf(a.w + bias[c + 3], 0.f);
            h[4] = (_Float16)fmaxf(b.x + bias[c + 4], 0.f);
            h[5] = (_Float16)fmaxf(b.y + bias[c + 5], 0.f);
            h[6] = (_Float16)fmaxf(b.z + bias[c + 6], 0.f);
            h[7] = (_Float16)fmaxf(b.w + bias[c + 7], 0.f);
        } else {
            #pragma unroll
            for (int j = 0; j < 8; ++j) h[j] = (_Float16)0.f;
        }
        *(f16x8*)&ah[r * HD + (c ^ ((r & 7) << 3))] = h;
    }
    __syncthreads();
    int lane = tid & 63, wv = tid >> 6;
    int lr = lane & 15, g = lane >> 4;
    f32x4 z = {0.f, 0.f, 0.f, 0.f};
    f32x4 acc[4] = {z, z, z, z};
    #pragma unroll
    for (int kk = 0; kk < 2; ++kk) {          // K = 64, 32 per step
        int kb = kk * 32 + g * 8;
        int ar = wv * 16 + lr;
        f16x8 af = *(const f16x8*)&ah[ar * HD + (kb ^ ((ar & 7) << 3))];
        #pragma unroll
        for (int ct = 0; ct < 4; ++ct) {
            int br = ct * 16 + lr;
            f16x8 bf = *(const f16x8*)&wh[br * HD + (kb ^ ((br & 7) << 3))];
            acc[ct] = __builtin_amdgcn_mfma_f32_16x16x32_f16(af, bf, acc[ct], 0, 0, 0);
        }
    }
    int r0 = base + wv * 16 + g * 4;
    #pragma unroll
    for (int j = 0; j < 4; ++j) {
        int row = r0 + j;
        if (row < N) {
            float dd = dinv[row];
            #pragma unroll
            for (int ct = 0; ct < 4; ++ct)
                th[(size_t)row * HD + ct * 16 + lr] = (_Float16)(acc[ct][j] * dd);
        }
    }
}

// ---- head: out = (a2 + b2) @ Wc + bc   [N,64]x[64,16] ----
__global__ __launch_bounds__(256) void final_kernel(
    const float* __restrict__ ain, const float* __restrict__ b2,
    const float* __restrict__ Wc, const float* __restrict__ bc,
    float* __restrict__ out, int N) {
    __shared__ float Ws[HD * OD];     // 4 KB
    __shared__ float hs[16][HD + 1];  // padded
    int tid = threadIdx.x;
    for (int i = tid; i < HD * OD; i += 256) Ws[i] = Wc[i];
    int base = blockIdx.x * 16;
    for (int i = tid; i < 16 * HD; i += 256) {
        int r = i >> 6, c = i & 63;
        int row = base + r;
        hs[r][c] = (row < N) ? ain[(size_t)row * HD + c] + b2[c] : 0.0f;
    }
    __syncthreads();
    int col = tid & 15, r = tid >> 4;
    int row = base + r;
    if (row < N) {
        float acc = bc[col];
        #pragma unroll
        for (int k = 0; k < HD; ++k)
            acc += hs[r][k] * Ws[k * OD + col];
        out[(size_t)row * OD + col] = acc;
    }
}

extern "C" void kernel_launch(void* const* d_in, const int* in_sizes, int n_in,
                              void* d_out, int out_size, void* d_ws, size_t ws_size,
                              hipStream_t stream) {
    const float* x  = (const float*)d_in[0];
    const int*   ei = (const int*)d_in[1];   // [2,E] flat int32
    const float* W1 = (const float*)d_in[2];
    const float* b1 = (const float*)d_in[3];
    const float* W2 = (const float*)d_in[4];
    const float* b2 = (const float*)d_in[5];
    const float* Wc = (const float*)d_in[6];
    const float* bc = (const float*)d_in[7];
    float* out = (float*)d_out;

    int N = in_sizes[0] / ID;   // 100000
    int E = in_sizes[1] / 2;    // 1600000 (multiple of 4)
    const int* src = ei;
    const int* dst = ei + E;
    int K = (N + RB - 1) / RB;  // 196 coarse buckets (K <= KMAX)
    int Npad = (N + 63) & ~63;

    char* p = (char*)d_ws;
    int*      cnt    = (int*)p;      p += KMAX * 4;
    int*      coff   = (int*)p;      p += (KMAX + 4) * 4;
    int*      cursor = (int*)p;      p += KMAX * 4;
    float*    dinv   = (float*)p;    p += (size_t)Npad * 4;
    int*      off    = (int*)p;      p += (size_t)(Npad + RB) * 4;
    _Float16* w1t    = (_Float16*)p; p += (size_t)HD * ID * 2;  // [64][128]
    _Float16* w2t    = (_Float16*)p; p += (size_t)HD * HD * 2;  // [64][64]
    unsigned* epk    = (unsigned*)p; p += (size_t)E * 4;        // bucketed edges
    int*      sse    = (int*)p;      p += (size_t)E * 4;        // CSR src
    _Float16* th     = (_Float16*)p; p += (size_t)N * HD * 2;   // dinv-premult msgs
    float*    a1     = (float*)p;    p += (size_t)N * HD * 4;   // agg out (reused)

    hipMemsetAsync(cnt, 0, (size_t)K * sizeof(int), stream);

    // dense CSR build (shared by both layers) + weight prep
    passA_kernel<<<512, 256, 0, stream>>>((const int4*)dst, cnt, E / 4, K);
    prep_kernel<<<32, 256, 0, stream>>>(W1, W2, w1t, w2t);
    cscan_kernel<<<1, KMAX, 0, stream>>>(cnt, coff, cursor, K, E);
    passB_kernel<<<(E + CHUNK - 1) / CHUNK, 256, 0, stream>>>(src, dst, cursor, epk, E);
    sortB_kernel<<<K, RB, 0, stream>>>(coff, epk, sse, off, dinv, N);

    // layer 1
    gemm1_kernel<<<(N + 63) / 64, 256, 0, stream>>>(x, w1t, dinv, th, N);
    pull_kernel<<<(N * 64 + 255) / 256, 256, 0, stream>>>(off, sse, dinv, th, a1, N);

    // layer 2
    gemm2_kernel<<<(N + 63) / 64, 256, 0, stream>>>(a1, w2t, b1, dinv, th, N);
    pull_kernel<<<(N * 64 + 255) / 256, 256, 0, stream>>>(off, sse, dinv, th, a1, N);

    // head
    final_kernel<<<(N + 15) / 16, 256, 0, stream>>>(a1, b2, Wc, bc, out, N);
}